// Round 18
// baseline (715.780 us; speedup 1.0000x reference)
//
#include <hip/hip_runtime.h>

// ---------------------------------------------------------------------------
// Round 17: R16 base (658us) + two chain cuts.
//  1. gru_init: 2-tile pipeline (1024 blocks x 2 tiles, dbuf 2x32KB LDS):
//     tile1's 16 f32 loads issued before tile0's MFMA+epilogue -> HBM latency
//     hidden. Live set 48acc+~76 VGPR ~= 124 <= 128 (spill tell: WRITE jump).
//  2. gru_nw + node_msg fused in ONE dispatch: node_msg computes dotA inline
//     (32 per-frame dots in LDS from L2-hot nh) -> dependency on gru_nw gone.
//  Kept: f16 edge state (eh16), fused gru_iter, LDS hv carry, NW hoist.
// ---------------------------------------------------------------------------

#define D_DIM 256
#define NNODE 32
#define NEDGE 992
#define EDGE_ROWS (128 * NEDGE)   // 126976
#define NODE_ROWS (128 * NNODE)   // 4096
#define BM 64
#define EGRID (EDGE_ROWS / BM)    // 1984
#define NGRID (NODE_ROWS / BM)    // 64
#define GI_OFF 32768
#define GI_STR 776

typedef _Float16 half8 __attribute__((ext_vector_type(8)));
typedef _Float16 half4v __attribute__((ext_vector_type(4)));
typedef __attribute__((ext_vector_type(4))) float f32x4;

__device__ __forceinline__ float sigf(float x) { return 1.0f / (1.0f + __expf(-x)); }
__device__ __forceinline__ float tanh_fast(float x) { return 2.0f / (1.0f + __expf(-2.0f * x)) - 1.0f; }
__device__ __forceinline__ float dot4(float4 a, float4 b) { return a.x*b.x + a.y*b.y + a.z*b.z + a.w*b.w; }

__global__ __launch_bounds__(64) void pack_w(const float* __restrict__ Wih,
                                             const float* __restrict__ Whh,
                                             _Float16* __restrict__ ph) {
  const int ct = blockIdx.x;
  const int ks = blockIdx.y;
  const int l = threadIdx.x;
  const int col = ct * 16 + (l & 15);
  const int kb = ks * 32 + (l >> 4) * 8;
  const float* src = (kb < 256) ? (Wih + col * 256 + kb) : (Whh + col * 256 + (kb - 256));
  half8 v;
  #pragma unroll
  for (int j = 0; j < 8; ++j) v[j] = (_Float16)src[j];
  *(half8*)(ph + ((ct * 16 + ks) * 64 + l) * 8) = v;
}

// ---- INIT GRU (h=0), 2-tile pipelined. Edge blocks bx<992, node blocks rest ----
__global__ __launch_bounds__(1024, 4) void gru_init(
    const float* __restrict__ xe, const float* __restrict__ xn,
    _Float16* __restrict__ eh16, float* __restrict__ hn,
    const _Float16* __restrict__ wpe, const _Float16* __restrict__ wpn,
    const float* __restrict__ ebih, const float* __restrict__ ebhh,
    const float* __restrict__ nbih, const float* __restrict__ nbhh) {
  __shared__ __align__(16) unsigned char lds[65536];  // 2 x 32KB
  const bool edge = blockIdx.x < (EGRID / 2);
  const float* xsrc = edge ? xe : xn;
  const _Float16* wp = edge ? wpe : wpn;
  const float* bih = edge ? ebih : nbih;
  const float* bhh = edge ? ebhh : nbhh;
  const int tb = edge ? (blockIdx.x * 2) : ((blockIdx.x - EGRID / 2) * 2);

  const int t = threadIdx.x;
  const int srow = t >> 4;
  const int skc = t & 15;
  const int w = t >> 6;
  const int l = t & 63;
  const int lq = l >> 4;
  const int lr = l & 15;
  const int swm = (lr & 7) << 4;
  const int swz = (srow & 7) << 4;

  const int col = w * 16 + lr;
  const float br = bih[col] + bhh[col];
  const float bz = bih[256 + col] + bhh[256 + col];
  const float bnx = bih[512 + col];
  const float bnh = bhh[512 + col];

  float4 xa[4];
  auto LOAD = [&](int tile) {
    const int rowg = tile * BM + srow;
    #pragma unroll
    for (int i = 0; i < 4; ++i)
      xa[i] = *(const float4*)(xsrc + rowg * D_DIM + (i >> 1) * 128 + skc * 8 + (i & 1) * 4);
  };
  auto STAGE = [&](int buf) {
    #pragma unroll
    for (int c = 0; c < 2; ++c) {
      half8 hx;
      const float* f0 = (const float*)&xa[c * 2];
      #pragma unroll
      for (int j = 0; j < 8; ++j) hx[j] = (_Float16)f0[j];
      *(half8*)(&lds[buf * 32768 + ((srow * 512 + c * 256 + skc * 16) ^ swz)]) = hx;
    }
  };

  f32x4 acc_r[4], acc_z[4], acc_nx[4];
  auto COMPUTE = [&](int buf) {
    const f32x4 zz = {0.f, 0.f, 0.f, 0.f};
    #pragma unroll
    for (int rf = 0; rf < 4; ++rf) { acc_r[rf] = zz; acc_z[rf] = zz; acc_nx[rf] = zz; }
    #pragma unroll
    for (int ksg = 0; ksg < 8; ++ksg) {
      half8 ah[4];
      #pragma unroll
      for (int rf = 0; rf < 4; ++rf)
        ah[rf] = *(const half8*)(&lds[buf * 32768 + (((rf * 16 + lr) * 512 + ksg * 64 + lq * 16) ^ swm)]);
      const half8 br_ = *(const half8*)(wp + (((0 * 16 + w) * 16 + ksg) * 64 + l) * 8);
      const half8 bz_ = *(const half8*)(wp + (((1 * 16 + w) * 16 + ksg) * 64 + l) * 8);
      const half8 bn_ = *(const half8*)(wp + (((2 * 16 + w) * 16 + ksg) * 64 + l) * 8);
      #pragma unroll
      for (int rf = 0; rf < 4; ++rf)
        acc_r[rf] = __builtin_amdgcn_mfma_f32_16x16x32_f16(ah[rf], br_, acc_r[rf], 0, 0, 0);
      #pragma unroll
      for (int rf = 0; rf < 4; ++rf)
        acc_z[rf] = __builtin_amdgcn_mfma_f32_16x16x32_f16(ah[rf], bz_, acc_z[rf], 0, 0, 0);
      #pragma unroll
      for (int rf = 0; rf < 4; ++rf)
        acc_nx[rf] = __builtin_amdgcn_mfma_f32_16x16x32_f16(ah[rf], bn_, acc_nx[rf], 0, 0, 0);
    }
  };

  auto EPILOGUE = [&](int tile, int buf) {
    const int rb = tile * BM;
    if (edge) {
      _Float16 sv[16];
      #pragma unroll
      for (int rf = 0; rf < 4; ++rf) {
        #pragma unroll
        for (int q = 0; q < 4; ++q) {
          const float r = sigf(acc_r[rf][q] + br);
          const float z = sigf(acc_z[rf][q] + bz);
          const float n = tanh_fast(acc_nx[rf][q] + bnx + r * bnh);
          sv[rf * 4 + q] = (_Float16)((1.0f - z) * n);
        }
      }
      __syncthreads();
      #pragma unroll
      for (int rf = 0; rf < 4; ++rf) {
        #pragma unroll
        for (int q = 0; q < 4; ++q) {
          const int rowl = rf * 16 + lq * 4 + q;
          *(_Float16*)(&lds[buf * 32768 + ((rowl * 512 + col * 2) ^ ((rowl & 7) << 4))]) = sv[rf * 4 + q];
        }
      }
      __syncthreads();
      #pragma unroll
      for (int p = 0; p < 2; ++p) {
        const int c = t + p * 1024;
        const int row = c >> 5;
        const int kc = c & 31;
        *(uint4*)(eh16 + (rb + row) * 256 + kc * 8) =
            *(const uint4*)(&lds[buf * 32768 + ((row * 512 + kc * 16) ^ ((row & 7) << 4))]);
      }
    } else {
      #pragma unroll
      for (int rf = 0; rf < 4; ++rf) {
        #pragma unroll
        for (int q = 0; q < 4; ++q) {
          const int rowl = rf * 16 + lq * 4 + q;
          const float r = sigf(acc_r[rf][q] + br);
          const float z = sigf(acc_z[rf][q] + bz);
          const float n = tanh_fast(acc_nx[rf][q] + bnx + r * bnh);
          hn[(rb + rowl) * D_DIM + col] = (1.0f - z) * n;
        }
      }
    }
  };

  // ---- pipeline: load0/stage0 -> [load1 in flight] compute0/epi0 -> stage1/compute1/epi1
  LOAD(tb); STAGE(0); __syncthreads();
  LOAD(tb + 1);
  COMPUTE(0);
  EPILOGUE(tb, 0);
  STAGE(1); __syncthreads();
  COMPUTE(1);
  EPILOGUE(tb + 1, 1);
}

// ---- fused: gru_nw (blocks [0,NGRID)) + node_msg (blocks [NGRID,NGRID+1024)) ----
__global__ __launch_bounds__(1024, 4) void gru_nw_msg(
    const float* __restrict__ nh, const _Float16* __restrict__ wp,
    _Float16* __restrict__ nw,
    const float* __restrict__ wnp, const float* __restrict__ wes,
    const float* __restrict__ weo,
    float* __restrict__ dS, float* __restrict__ dO,
    const _Float16* __restrict__ eh16, float* __restrict__ nmsg) {
  __shared__ __align__(16) unsigned char lds[32768];
  const int t = threadIdx.x;

  if (blockIdx.x < NGRID) {
    // ================= NW GEMM + fused dotS/dotO =================
    const int rb = blockIdx.x * BM;
    const int srow = t >> 4;
    const int skc = t & 15;
    const int w = t >> 6;
    const int l = t & 63;
    const int lq = l >> 4;
    const int lr = l & 15;
    const int swm = (lr & 7) << 4;
    const int swz = (srow & 7) << 4;
    const int rowg = rb + srow;

    float4 xa[4];
    #pragma unroll
    for (int i = 0; i < 4; ++i)
      xa[i] = *(const float4*)(nh + rowg * D_DIM + (i >> 1) * 128 + skc * 8 + (i & 1) * 4);
    #pragma unroll
    for (int c = 0; c < 2; ++c) {
      half8 hx;
      const float* f0 = (const float*)&xa[c * 2];
      #pragma unroll
      for (int j = 0; j < 8; ++j) hx[j] = (_Float16)f0[j];
      *(half8*)(&lds[(srow * 512 + c * 256 + skc * 16) ^ swz]) = hx;
    }
    float p2 = 0.f, p3 = 0.f;
    #pragma unroll
    for (int i = 0; i < 4; ++i) {
      const int k0 = (i >> 1) * 128 + skc * 8 + (i & 1) * 4;
      p2 += dot4(xa[i], *(const float4*)(wes + k0));
      p3 += dot4(xa[i], *(const float4*)(weo + k0));
    }
    #pragma unroll
    for (int mm = 1; mm < 16; mm <<= 1) {
      p2 += __shfl_xor(p2, mm, 16);
      p3 += __shfl_xor(p3, mm, 16);
    }
    if (skc == 0) { dS[rowg] = p2; dO[rowg] = p3; }
    __syncthreads();

    const f32x4 zz = {0.f, 0.f, 0.f, 0.f};
    f32x4 acc_r[4] = {zz, zz, zz, zz};
    f32x4 acc_z[4] = {zz, zz, zz, zz};
    f32x4 acc_nx[4] = {zz, zz, zz, zz};

    #pragma unroll
    for (int ksg = 0; ksg < 8; ++ksg) {
      half8 ah[4];
      #pragma unroll
      for (int rf = 0; rf < 4; ++rf)
        ah[rf] = *(const half8*)(&lds[((rf * 16 + lr) * 512 + ksg * 64 + lq * 16) ^ swm]);
      const half8 br_ = *(const half8*)(wp + (((0 * 16 + w) * 16 + ksg) * 64 + l) * 8);
      const half8 bz_ = *(const half8*)(wp + (((1 * 16 + w) * 16 + ksg) * 64 + l) * 8);
      const half8 bn_ = *(const half8*)(wp + (((2 * 16 + w) * 16 + ksg) * 64 + l) * 8);
      #pragma unroll
      for (int rf = 0; rf < 4; ++rf)
        acc_r[rf] = __builtin_amdgcn_mfma_f32_16x16x32_f16(ah[rf], br_, acc_r[rf], 0, 0, 0);
      #pragma unroll
      for (int rf = 0; rf < 4; ++rf)
        acc_z[rf] = __builtin_amdgcn_mfma_f32_16x16x32_f16(ah[rf], bz_, acc_z[rf], 0, 0, 0);
      #pragma unroll
      for (int rf = 0; rf < 4; ++rf)
        acc_nx[rf] = __builtin_amdgcn_mfma_f32_16x16x32_f16(ah[rf], bn_, acc_nx[rf], 0, 0, 0);
    }

    const int col = w * 16 + lr;
    #pragma unroll
    for (int rf = 0; rf < 4; ++rf) {
      #pragma unroll
      for (int q = 0; q < 4; ++q) {
        const int rowl = rf * 16 + lq * 4 + q;
        _Float16* np = nw + (rb + rowl) * 768 + col;
        np[0]   = (_Float16)acc_r[rf][q];
        np[256] = (_Float16)acc_z[rf][q];
        np[512] = (_Float16)acc_nx[rf][q];
      }
    }
  } else {
    // ================= node_msg: 4 nodes per block, inline dotA =================
    float (*sh)[3][256] = (float (*)[3][256])lds;      // 12 KB
    float* dotA_s = (float*)(lds + 12288);             // 32 floats
    const int nb = blockIdx.x - NGRID;                 // 0..1023
    const int b = nb >> 3;                             // frame
    const int wg = t >> 6;                             // 0..15
    const int l = t & 63;
    const int base = b * NEDGE;
    const float4 w1a = ((const float4*)wnp)[l];
    const float4 w1b = ((const float4*)(wnp + 256))[l];

    // dotA for all 32 nodes of frame b (2 per wave)
    #pragma unroll
    for (int u = 0; u < 2; ++u) {
      const int nn = wg * 2 + u;
      float p = dot4(((const float4*)(nh + (b * NNODE + nn) * D_DIM))[l], w1a);
      #pragma unroll
      for (int mm = 32; mm > 0; mm >>= 1) p += __shfl_xor(p, mm, 64);
      if (l == 0) dotA_s[nn] = p;
    }
    __syncthreads();

    const int node_local = wg >> 2;   // 0..3
    const int wv = wg & 3;
    const int n = (nb & 7) * 4 + node_local;
    const int nr = b * NNODE + n;

    float4 acc = {0.f, 0.f, 0.f, 0.f};
    for (int k = wv; k < 62; k += 4) {
      int e, sub;
      if (k < 31) {
        e = base + n * 31 + k;
        sub = n;
      } else {
        int i = k - 31;
        const int ip = (i < n) ? i : (i + 1);
        e = base + ip * 31 + ((n < ip) ? n : (n - 1));
        sub = ip;
      }
      const half4v hv4 = ((const half4v*)(eh16 + e * 256))[l];
      float4 ev;
      ev.x = (float)hv4[0]; ev.y = (float)hv4[1];
      ev.z = (float)hv4[2]; ev.w = (float)hv4[3];
      float p = dot4(ev, w1b);
      #pragma unroll
      for (int mm = 32; mm > 0; mm >>= 1) p += __shfl_xor(p, mm, 64);
      const float gN = sigf(dotA_s[sub] + p);
      acc.x += gN * ev.x; acc.y += gN * ev.y; acc.z += gN * ev.z; acc.w += gN * ev.w;
    }
    if (wv > 0) *(float4*)(&sh[node_local][wv - 1][l * 4]) = acc;
    __syncthreads();
    if (wv == 0) {
      #pragma unroll
      for (int v = 0; v < 3; ++v) {
        const float4 o = *(const float4*)(&sh[node_local][v][l * 4]);
        acc.x += o.x; acc.y += o.y; acc.z += o.z; acc.w += o.w;
      }
      *(float4*)(nmsg + nr * D_DIM + l * 4) = acc;
    }
  }
}

// ---- fused iteration GRU (unchanged from R16) ----
template <bool LAST>
__global__ __launch_bounds__(1024, 4) void gru_iter(
    _Float16* __restrict__ eh16, float* __restrict__ ehf,
    float* __restrict__ nh, const float* __restrict__ nmsg,
    const _Float16* __restrict__ wpe, const _Float16* __restrict__ wpn,
    const float* __restrict__ ebih, const float* __restrict__ ebhh,
    const float* __restrict__ nbih, const float* __restrict__ nbhh,
    const float* __restrict__ wesb, const float* __restrict__ weob,
    const float* __restrict__ dotS, const float* __restrict__ dotO,
    const _Float16* __restrict__ nw) {
  __shared__ __align__(16) unsigned char lds[32768 + BM * GI_STR * 2];

  const int t = threadIdx.x;
  const int srow = t >> 4;
  const int skc = t & 15;
  const int w = t >> 6;
  const int l = t & 63;
  const int lq = l >> 4;
  const int lr = l & 15;
  const int swm = (lr & 7) << 4;
  const int swz = (srow & 7) << 4;

  const f32x4 zz = {0.f, 0.f, 0.f, 0.f};
  f32x4 acc_r[4] = {zz, zz, zz, zz};
  f32x4 acc_z[4] = {zz, zz, zz, zz};
  f32x4 acc_nx[4] = {zz, zz, zz, zz};
  f32x4 acc_nh[4] = {zz, zz, zz, zz};

  if (blockIdx.x < EGRID) {
    const int rb = blockIdx.x * BM;
    const int rowg = rb + srow;
    const int b = rowg / NEDGE;
    const int e = rowg - b * NEDGE;
    const int si = e / 31;
    const int m = e - si * 31;
    const int ob = (m < si) ? m : (m + 1);

    const uint4 v0 = *(const uint4*)(eh16 + rowg * 256 + skc * 8);
    const uint4 v1 = *(const uint4*)(eh16 + rowg * 256 + 128 + skc * 8);
    *(uint4*)(&lds[(srow * 512 + skc * 16) ^ swz]) = v0;
    *(uint4*)(&lds[(srow * 512 + 256 + skc * 16) ^ swz]) = v1;
    float pS = 0.f, pO = 0.f;
    {
      const _Float16* f0 = (const _Float16*)&v0;
      const _Float16* f1 = (const _Float16*)&v1;
      #pragma unroll
      for (int j = 0; j < 8; ++j) {
        const float a = (float)f0[j];
        const float bb = (float)f1[j];
        pS += a * wesb[skc * 8 + j] + bb * wesb[128 + skc * 8 + j];
        pO += a * weob[skc * 8 + j] + bb * weob[128 + skc * 8 + j];
      }
    }
    #pragma unroll
    for (int mm = 1; mm < 16; mm <<= 1) {
      pS += __shfl_xor(pS, mm, 16);
      pO += __shfl_xor(pO, mm, 16);
    }
    const float gs = sigf(dotS[b * NNODE + si] + pS);
    const float go = sigf(dotO[b * NNODE + ob] + pO);
    const _Float16 gsh = (_Float16)gs, goh = (_Float16)go;
    const _Float16* ns = nw + (b * NNODE + si) * 768;
    const _Float16* no_ = nw + (b * NNODE + ob) * 768;
    _Float16* giw = (_Float16*)(lds + GI_OFF) + srow * GI_STR;
    #pragma unroll
    for (int j = 0; j < 6; ++j) {
      const int c0 = skc * 8 + j * 128;
      const half8 a = *(const half8*)(ns + c0);
      const half8 bb = *(const half8*)(no_ + c0);
      half8 g;
      #pragma unroll
      for (int k = 0; k < 8; ++k) g[k] = gsh * a[k] + goh * bb[k];
      *(half8*)(giw + c0) = g;
    }
    __syncthreads();

    #pragma unroll
    for (int ksg = 0; ksg < 8; ++ksg) {
      half8 ah[4];
      #pragma unroll
      for (int rf = 0; rf < 4; ++rf)
        ah[rf] = *(const half8*)(&lds[((rf * 16 + lr) * 512 + ksg * 64 + lq * 16) ^ swm]);
      const int kk = 8 + ksg;
      const half8 br_ = *(const half8*)(wpe + (((0 * 16 + w) * 16 + kk) * 64 + l) * 8);
      const half8 bz_ = *(const half8*)(wpe + (((1 * 16 + w) * 16 + kk) * 64 + l) * 8);
      const half8 bn_ = *(const half8*)(wpe + (((2 * 16 + w) * 16 + kk) * 64 + l) * 8);
      #pragma unroll
      for (int rf = 0; rf < 4; ++rf)
        acc_r[rf] = __builtin_amdgcn_mfma_f32_16x16x32_f16(ah[rf], br_, acc_r[rf], 0, 0, 0);
      #pragma unroll
      for (int rf = 0; rf < 4; ++rf)
        acc_z[rf] = __builtin_amdgcn_mfma_f32_16x16x32_f16(ah[rf], bz_, acc_z[rf], 0, 0, 0);
      #pragma unroll
      for (int rf = 0; rf < 4; ++rf)
        acc_nh[rf] = __builtin_amdgcn_mfma_f32_16x16x32_f16(ah[rf], bn_, acc_nh[rf], 0, 0, 0);
    }

    const int col = w * 16 + lr;
    const float br = ebih[col] + ebhh[col];
    const float bz = ebih[256 + col] + ebhh[256 + col];
    const float bnx = ebih[512 + col];
    const float bnh = ebhh[512 + col];
    const _Float16* gir = (const _Float16*)(lds + GI_OFF);
    _Float16 sv[16];
    #pragma unroll
    for (int rf = 0; rf < 4; ++rf) {
      #pragma unroll
      for (int q = 0; q < 4; ++q) {
        const int rowl = rf * 16 + lq * 4 + q;
        const _Float16* gp = gir + rowl * GI_STR + col;
        const float r = sigf(acc_r[rf][q] + (float)gp[0] + br);
        const float z = sigf(acc_z[rf][q] + (float)gp[256] + bz);
        const float n = tanh_fast((float)gp[512] + bnx + r * (acc_nh[rf][q] + bnh));
        const float hv =
            (float)*(const _Float16*)(&lds[(rowl * 512 + col * 2) ^ ((rowl & 7) << 4)]);
        const float out = (1.0f - z) * n + z * hv;
        if constexpr (LAST) {
          ehf[(rb + rowl) * D_DIM + col] = out;
        } else {
          sv[rf * 4 + q] = (_Float16)out;
        }
      }
    }
    if constexpr (!LAST) {
      __syncthreads();
      #pragma unroll
      for (int rf = 0; rf < 4; ++rf) {
        #pragma unroll
        for (int q = 0; q < 4; ++q) {
          const int rowl = rf * 16 + lq * 4 + q;
          *(_Float16*)(&lds[(rowl * 512 + col * 2) ^ ((rowl & 7) << 4)]) = sv[rf * 4 + q];
        }
      }
      __syncthreads();
      #pragma unroll
      for (int p = 0; p < 2; ++p) {
        const int c = t + p * 1024;
        const int row = c >> 5;
        const int kc = c & 31;
        *(uint4*)(eh16 + (rb + row) * 256 + kc * 8) =
            *(const uint4*)(&lds[(row * 512 + kc * 16) ^ ((row & 7) << 4)]);
      }
    }
  } else {
    const int rb = (blockIdx.x - EGRID) * BM;
    const int rowg = rb + srow;

    {
      float4 pre[4];
      #pragma unroll
      for (int i = 0; i < 4; ++i)
        pre[i] = *(const float4*)(nh + rowg * D_DIM + (i >> 1) * 128 + skc * 8 + (i & 1) * 4);
      #pragma unroll
      for (int c = 0; c < 2; ++c) {
        half8 hh8;
        const float* f1 = (const float*)&pre[c * 2];
        #pragma unroll
        for (int j = 0; j < 8; ++j) hh8[j] = (_Float16)f1[j];
        *(half8*)(&lds[(srow * 1024 + 512 + c * 256 + skc * 16) ^ swz]) = hh8;
      }
    }
    __syncthreads();

    #pragma unroll
    for (int ksg = 0; ksg < 8; ++ksg) {
      half8 ah[4];
      #pragma unroll
      for (int rf = 0; rf < 4; ++rf)
        ah[rf] = *(const half8*)(&lds[((rf * 16 + lr) * 1024 + 512 + ksg * 64 + lq * 16) ^ swm]);
      const int kk = 8 + ksg;
      const half8 br_ = *(const half8*)(wpn + (((0 * 16 + w) * 16 + kk) * 64 + l) * 8);
      const half8 bz_ = *(const half8*)(wpn + (((1 * 16 + w) * 16 + kk) * 64 + l) * 8);
      const half8 bn_ = *(const half8*)(wpn + (((2 * 16 + w) * 16 + kk) * 64 + l) * 8);
      #pragma unroll
      for (int rf = 0; rf < 4; ++rf)
        acc_r[rf] = __builtin_amdgcn_mfma_f32_16x16x32_f16(ah[rf], br_, acc_r[rf], 0, 0, 0);
      #pragma unroll
      for (int rf = 0; rf < 4; ++rf)
        acc_z[rf] = __builtin_amdgcn_mfma_f32_16x16x32_f16(ah[rf], bz_, acc_z[rf], 0, 0, 0);
      #pragma unroll
      for (int rf = 0; rf < 4; ++rf)
        acc_nh[rf] = __builtin_amdgcn_mfma_f32_16x16x32_f16(ah[rf], bn_, acc_nh[rf], 0, 0, 0);
    }

    #pragma unroll
    for (int c = 0; c < 2; ++c) {
      half8 hx;
      #pragma unroll
      for (int pq = 0; pq < 2; ++pq) {
        const float4 a = *(const float4*)(nmsg + rowg * D_DIM + c * 128 + skc * 8 + pq * 4);
        hx[pq * 4 + 0] = (_Float16)a.x; hx[pq * 4 + 1] = (_Float16)a.y;
        hx[pq * 4 + 2] = (_Float16)a.z; hx[pq * 4 + 3] = (_Float16)a.w;
      }
      *(half8*)(&lds[(srow * 1024 + 0 + c * 256 + skc * 16) ^ swz]) = hx;
    }
    __syncthreads();
    #pragma unroll
    for (int ksg = 0; ksg < 8; ++ksg) {
      half8 ah[4];
      #pragma unroll
      for (int rf = 0; rf < 4; ++rf)
        ah[rf] = *(const half8*)(&lds[((rf * 16 + lr) * 1024 + 0 + ksg * 64 + lq * 16) ^ swm]);
      const half8 br_ = *(const half8*)(wpn + (((0 * 16 + w) * 16 + ksg) * 64 + l) * 8);
      const half8 bz_ = *(const half8*)(wpn + (((1 * 16 + w) * 16 + ksg) * 64 + l) * 8);
      const half8 bn_ = *(const half8*)(wpn + (((2 * 16 + w) * 16 + ksg) * 64 + l) * 8);
      #pragma unroll
      for (int rf = 0; rf < 4; ++rf)
        acc_r[rf] = __builtin_amdgcn_mfma_f32_16x16x32_f16(ah[rf], br_, acc_r[rf], 0, 0, 0);
      #pragma unroll
      for (int rf = 0; rf < 4; ++rf)
        acc_z[rf] = __builtin_amdgcn_mfma_f32_16x16x32_f16(ah[rf], bz_, acc_z[rf], 0, 0, 0);
      #pragma unroll
      for (int rf = 0; rf < 4; ++rf)
        acc_nx[rf] = __builtin_amdgcn_mfma_f32_16x16x32_f16(ah[rf], bn_, acc_nx[rf], 0, 0, 0);
    }

    const int col = w * 16 + lr;
    const float br = nbih[col] + nbhh[col];
    const float bz = nbih[256 + col] + nbhh[256 + col];
    const float bnx = nbih[512 + col];
    const float bnh = nbhh[512 + col];
    #pragma unroll
    for (int rf = 0; rf < 4; ++rf) {
      #pragma unroll
      for (int q = 0; q < 4; ++q) {
        const int rowl = rf * 16 + lq * 4 + q;
        const float r = sigf(acc_r[rf][q] + br);
        const float z = sigf(acc_z[rf][q] + bz);
        const float n = tanh_fast(acc_nx[rf][q] + bnx + r * (acc_nh[rf][q] + bnh));
        const float hv = nh[(rb + rowl) * D_DIM + col];
        nh[(rb + rowl) * D_DIM + col] = (1.0f - z) * n + z * hv;
      }
    }
  }
}

extern "C" void kernel_launch(void* const* d_in, const int* in_sizes, int n_in,
                              void* d_out, int out_size, void* d_ws, size_t ws_size,
                              hipStream_t stream) {
  const float* node_latents = (const float*)d_in[0];
  const float* edge_latents = (const float*)d_in[1];
  const float* node_Wih = (const float*)d_in[2];
  const float* node_Whh = (const float*)d_in[3];
  const float* node_bih = (const float*)d_in[4];
  const float* node_bhh = (const float*)d_in[5];
  const float* edge_Wih = (const float*)d_in[6];
  const float* edge_Whh = (const float*)d_in[7];
  const float* edge_bih = (const float*)d_in[8];
  const float* edge_bhh = (const float*)d_in[9];
  const float* w_node_pool = (const float*)d_in[10];
  const float* w_edge_sub = (const float*)d_in[11];
  const float* w_edge_obj = (const float*)d_in[12];

  float* nh = (float*)d_out;
  float* eh = (float*)d_out + NODE_ROWS * D_DIM;

  const int WPLANE = 48 * 16 * 64 * 8;  // 768KB
  _Float16* ph_n = (_Float16*)d_ws;
  _Float16* ph_e = ph_n + WPLANE;
  _Float16* NW = ph_e + WPLANE;                    // 6 MB
  _Float16* eh16 = NW + NODE_ROWS * 768;           // 65 MB
  float* fw = (float*)(eh16 + (size_t)EDGE_ROWS * D_DIM);
  float* dotS = fw; fw += NODE_ROWS;
  float* dotO = fw; fw += NODE_ROWS;
  float* node_msg = fw; fw += NODE_ROWS * D_DIM;   // total ~77 MB

  dim3 pg(48, 16);
  pack_w<<<pg, 64, 0, stream>>>(node_Wih, node_Whh, ph_n);
  pack_w<<<pg, 64, 0, stream>>>(edge_Wih, edge_Whh, ph_e);

  gru_init<<<(EGRID + NGRID) / 2, 1024, 0, stream>>>(
      edge_latents, node_latents, eh16, nh, ph_e, ph_n,
      edge_bih, edge_bhh, node_bih, node_bhh);

  for (int it = 0; it < 3; ++it) {
    gru_nw_msg<<<NGRID + 1024, 1024, 0, stream>>>(
        nh, ph_e, NW, w_node_pool, w_edge_sub, w_edge_obj,
        dotS, dotO, eh16, node_msg);
    if (it < 2)
      gru_iter<false><<<EGRID + NGRID, 1024, 0, stream>>>(
          eh16, eh, nh, node_msg, ph_e, ph_n,
          edge_bih, edge_bhh, node_bih, node_bhh,
          w_edge_sub + 256, w_edge_obj + 256, dotS, dotO, NW);
    else
      gru_iter<true><<<EGRID + NGRID, 1024, 0, stream>>>(
          eh16, eh, nh, node_msg, ph_e, ph_n,
          edge_bih, edge_bhh, node_bih, node_bhh,
          w_edge_sub + 256, w_edge_obj + 256, dotS, dotO, NW);
  }
}

// Round 19
// 656.414 us; speedup vs baseline: 1.0904x; 1.0904x over previous
//
#include <hip/hip_runtime.h>

// ---------------------------------------------------------------------------
// Round 18: consolidation — R16 verbatim (best proven: 658us, absmax 0.0078).
//  R17's two changes both regressed and are reverted:
//   - init 2-tile pipeline: spilled (WRITE 67->174MB) — R7/R8 trap confirmed.
//   - nw+msg fusion: +8us/iter (queueing + redundant per-block dotA).
//  Falsified-lever ledger (do not retry): co-residency (R10/R12, register
//  wall), persistence (R5, L2 thrash), intra-block pipeline (R17, spill),
//  staging-chain cuts (R13/R14, not critical-path), extra fusion (R17).
//  Surviving structure: MFMA f16 GEMMs, NW hoist, R15 dispatch fusion,
//  f16 edge state (eh16), LDS hv carry, fused dot3.
// ---------------------------------------------------------------------------

#define D_DIM 256
#define NNODE 32
#define NEDGE 992
#define EDGE_ROWS (128 * NEDGE)   // 126976
#define NODE_ROWS (128 * NNODE)   // 4096
#define BM 64
#define EGRID (EDGE_ROWS / BM)    // 1984
#define NGRID (NODE_ROWS / BM)    // 64
#define GI_OFF 32768
#define GI_STR 776

typedef _Float16 half8 __attribute__((ext_vector_type(8)));
typedef _Float16 half4v __attribute__((ext_vector_type(4)));
typedef __attribute__((ext_vector_type(4))) float f32x4;

__device__ __forceinline__ float sigf(float x) { return 1.0f / (1.0f + __expf(-x)); }
__device__ __forceinline__ float tanh_fast(float x) { return 2.0f / (1.0f + __expf(-2.0f * x)) - 1.0f; }
__device__ __forceinline__ float dot4(float4 a, float4 b) { return a.x*b.x + a.y*b.y + a.z*b.z + a.w*b.w; }

__global__ __launch_bounds__(64) void pack_w(const float* __restrict__ Wih,
                                             const float* __restrict__ Whh,
                                             _Float16* __restrict__ ph) {
  const int ct = blockIdx.x;
  const int ks = blockIdx.y;
  const int l = threadIdx.x;
  const int col = ct * 16 + (l & 15);
  const int kb = ks * 32 + (l >> 4) * 8;
  const float* src = (kb < 256) ? (Wih + col * 256 + kb) : (Whh + col * 256 + (kb - 256));
  half8 v;
  #pragma unroll
  for (int j = 0; j < 8; ++j) v[j] = (_Float16)src[j];
  *(half8*)(ph + ((ct * 16 + ks) * 64 + l) * 8) = v;
}

// ---- INIT GRU (h=0): edge blocks write eh16; node blocks write f32 nh ----
__global__ __launch_bounds__(1024, 4) void gru_init(
    const float* __restrict__ xe, const float* __restrict__ xn,
    _Float16* __restrict__ eh16, float* __restrict__ hn,
    const _Float16* __restrict__ wpe, const _Float16* __restrict__ wpn,
    const float* __restrict__ ebih, const float* __restrict__ ebhh,
    const float* __restrict__ nbih, const float* __restrict__ nbhh) {
  __shared__ __align__(16) unsigned char lds[32768];
  const bool edge = blockIdx.x < EGRID;
  const int bx = edge ? blockIdx.x : (blockIdx.x - EGRID);
  const float* xsrc = edge ? xe : xn;
  const _Float16* wp = edge ? wpe : wpn;
  const float* bih = edge ? ebih : nbih;
  const float* bhh = edge ? ebhh : nbhh;

  const int t = threadIdx.x;
  const int rb = bx * BM;
  const int srow = t >> 4;
  const int skc = t & 15;
  const int w = t >> 6;
  const int l = t & 63;
  const int lq = l >> 4;
  const int lr = l & 15;
  const int swm = (lr & 7) << 4;
  const int swz = (srow & 7) << 4;
  const int rowg = rb + srow;

  #pragma unroll
  for (int c = 0; c < 2; ++c) {
    half8 hx;
    #pragma unroll
    for (int pq = 0; pq < 2; ++pq) {
      const float4 a = *(const float4*)(xsrc + rowg * D_DIM + c * 128 + skc * 8 + pq * 4);
      hx[pq * 4 + 0] = (_Float16)a.x; hx[pq * 4 + 1] = (_Float16)a.y;
      hx[pq * 4 + 2] = (_Float16)a.z; hx[pq * 4 + 3] = (_Float16)a.w;
    }
    *(half8*)(&lds[(srow * 512 + c * 256 + skc * 16) ^ swz]) = hx;
  }
  __syncthreads();

  const f32x4 zz = {0.f, 0.f, 0.f, 0.f};
  f32x4 acc_r[4] = {zz, zz, zz, zz};
  f32x4 acc_z[4] = {zz, zz, zz, zz};
  f32x4 acc_nx[4] = {zz, zz, zz, zz};

  #pragma unroll
  for (int ksg = 0; ksg < 8; ++ksg) {
    half8 ah[4];
    #pragma unroll
    for (int rf = 0; rf < 4; ++rf)
      ah[rf] = *(const half8*)(&lds[((rf * 16 + lr) * 512 + ksg * 64 + lq * 16) ^ swm]);
    const half8 br_ = *(const half8*)(wp + (((0 * 16 + w) * 16 + ksg) * 64 + l) * 8);
    const half8 bz_ = *(const half8*)(wp + (((1 * 16 + w) * 16 + ksg) * 64 + l) * 8);
    const half8 bn_ = *(const half8*)(wp + (((2 * 16 + w) * 16 + ksg) * 64 + l) * 8);
    #pragma unroll
    for (int rf = 0; rf < 4; ++rf)
      acc_r[rf] = __builtin_amdgcn_mfma_f32_16x16x32_f16(ah[rf], br_, acc_r[rf], 0, 0, 0);
    #pragma unroll
    for (int rf = 0; rf < 4; ++rf)
      acc_z[rf] = __builtin_amdgcn_mfma_f32_16x16x32_f16(ah[rf], bz_, acc_z[rf], 0, 0, 0);
    #pragma unroll
    for (int rf = 0; rf < 4; ++rf)
      acc_nx[rf] = __builtin_amdgcn_mfma_f32_16x16x32_f16(ah[rf], bn_, acc_nx[rf], 0, 0, 0);
  }

  const int col = w * 16 + lr;
  const float br = bih[col] + bhh[col];
  const float bz = bih[256 + col] + bhh[256 + col];
  const float bnx = bih[512 + col];
  const float bnh = bhh[512 + col];

  if (edge) {
    _Float16 sv[16];
    #pragma unroll
    for (int rf = 0; rf < 4; ++rf) {
      #pragma unroll
      for (int q = 0; q < 4; ++q) {
        const float r = sigf(acc_r[rf][q] + br);
        const float z = sigf(acc_z[rf][q] + bz);
        const float n = tanh_fast(acc_nx[rf][q] + bnx + r * bnh);
        sv[rf * 4 + q] = (_Float16)((1.0f - z) * n);
      }
    }
    __syncthreads();
    #pragma unroll
    for (int rf = 0; rf < 4; ++rf) {
      #pragma unroll
      for (int q = 0; q < 4; ++q) {
        const int rowl = rf * 16 + lq * 4 + q;
        *(_Float16*)(&lds[(rowl * 512 + col * 2) ^ ((rowl & 7) << 4)]) = sv[rf * 4 + q];
      }
    }
    __syncthreads();
    #pragma unroll
    for (int p = 0; p < 2; ++p) {
      const int c = t + p * 1024;
      const int row = c >> 5;
      const int kc = c & 31;
      *(uint4*)(eh16 + (rb + row) * 256 + kc * 8) =
          *(const uint4*)(&lds[(row * 512 + kc * 16) ^ ((row & 7) << 4)]);
    }
  } else {
    #pragma unroll
    for (int rf = 0; rf < 4; ++rf) {
      #pragma unroll
      for (int q = 0; q < 4; ++q) {
        const int rowl = rf * 16 + lq * 4 + q;
        const float r = sigf(acc_r[rf][q] + br);
        const float z = sigf(acc_z[rf][q] + bz);
        const float n = tanh_fast(acc_nx[rf][q] + bnx + r * bnh);
        hn[(rb + rowl) * D_DIM + col] = (1.0f - z) * n;
      }
    }
  }
}

// ---- NW = nh @ edge_WihT (f16 out) with dot3 fused into staging ----
__global__ __launch_bounds__(1024, 4) void gru_nw(
    const float* __restrict__ nh, const _Float16* __restrict__ wp,
    _Float16* __restrict__ nw,
    const float* __restrict__ wnp, const float* __restrict__ wes,
    const float* __restrict__ weo,
    float* __restrict__ dA, float* __restrict__ dS, float* __restrict__ dO) {
  __shared__ __align__(16) unsigned char lds[32768];
  const int t = threadIdx.x;
  const int rb = blockIdx.x * BM;
  const int srow = t >> 4;
  const int skc = t & 15;
  const int w = t >> 6;
  const int l = t & 63;
  const int lq = l >> 4;
  const int lr = l & 15;
  const int swm = (lr & 7) << 4;
  const int swz = (srow & 7) << 4;
  const int rowg = rb + srow;

  float4 xa[4];
  #pragma unroll
  for (int i = 0; i < 4; ++i)
    xa[i] = *(const float4*)(nh + rowg * D_DIM + (i >> 1) * 128 + skc * 8 + (i & 1) * 4);
  #pragma unroll
  for (int c = 0; c < 2; ++c) {
    half8 hx;
    const float* f0 = (const float*)&xa[c * 2];
    #pragma unroll
    for (int j = 0; j < 8; ++j) hx[j] = (_Float16)f0[j];
    *(half8*)(&lds[(srow * 512 + c * 256 + skc * 16) ^ swz]) = hx;
  }
  float p1 = 0.f, p2 = 0.f, p3 = 0.f;
  #pragma unroll
  for (int i = 0; i < 4; ++i) {
    const int k0 = (i >> 1) * 128 + skc * 8 + (i & 1) * 4;
    p1 += dot4(xa[i], *(const float4*)(wnp + k0));
    p2 += dot4(xa[i], *(const float4*)(wes + k0));
    p3 += dot4(xa[i], *(const float4*)(weo + k0));
  }
  #pragma unroll
  for (int mm = 1; mm < 16; mm <<= 1) {
    p1 += __shfl_xor(p1, mm, 16);
    p2 += __shfl_xor(p2, mm, 16);
    p3 += __shfl_xor(p3, mm, 16);
  }
  if (skc == 0) { dA[rowg] = p1; dS[rowg] = p2; dO[rowg] = p3; }
  __syncthreads();

  const f32x4 zz = {0.f, 0.f, 0.f, 0.f};
  f32x4 acc_r[4] = {zz, zz, zz, zz};
  f32x4 acc_z[4] = {zz, zz, zz, zz};
  f32x4 acc_nx[4] = {zz, zz, zz, zz};

  #pragma unroll
  for (int ksg = 0; ksg < 8; ++ksg) {
    half8 ah[4];
    #pragma unroll
    for (int rf = 0; rf < 4; ++rf)
      ah[rf] = *(const half8*)(&lds[((rf * 16 + lr) * 512 + ksg * 64 + lq * 16) ^ swm]);
    const half8 br_ = *(const half8*)(wp + (((0 * 16 + w) * 16 + ksg) * 64 + l) * 8);
    const half8 bz_ = *(const half8*)(wp + (((1 * 16 + w) * 16 + ksg) * 64 + l) * 8);
    const half8 bn_ = *(const half8*)(wp + (((2 * 16 + w) * 16 + ksg) * 64 + l) * 8);
    #pragma unroll
    for (int rf = 0; rf < 4; ++rf)
      acc_r[rf] = __builtin_amdgcn_mfma_f32_16x16x32_f16(ah[rf], br_, acc_r[rf], 0, 0, 0);
    #pragma unroll
    for (int rf = 0; rf < 4; ++rf)
      acc_z[rf] = __builtin_amdgcn_mfma_f32_16x16x32_f16(ah[rf], bz_, acc_z[rf], 0, 0, 0);
    #pragma unroll
    for (int rf = 0; rf < 4; ++rf)
      acc_nx[rf] = __builtin_amdgcn_mfma_f32_16x16x32_f16(ah[rf], bn_, acc_nx[rf], 0, 0, 0);
  }

  const int col = w * 16 + lr;
  #pragma unroll
  for (int rf = 0; rf < 4; ++rf) {
    #pragma unroll
    for (int q = 0; q < 4; ++q) {
      const int rowl = rf * 16 + lq * 4 + q;
      _Float16* np = nw + (rb + rowl) * 768 + col;
      np[0]   = (_Float16)acc_r[rf][q];
      np[256] = (_Float16)acc_z[rf][q];
      np[512] = (_Float16)acc_nx[rf][q];
    }
  }
}

// ---- fused iteration GRU: edge blocks [0,EGRID) on eh16, node blocks rest ----
template <bool LAST>
__global__ __launch_bounds__(1024, 4) void gru_iter(
    _Float16* __restrict__ eh16, float* __restrict__ ehf,
    float* __restrict__ nh, const float* __restrict__ nmsg,
    const _Float16* __restrict__ wpe, const _Float16* __restrict__ wpn,
    const float* __restrict__ ebih, const float* __restrict__ ebhh,
    const float* __restrict__ nbih, const float* __restrict__ nbhh,
    const float* __restrict__ wesb, const float* __restrict__ weob,
    const float* __restrict__ dotS, const float* __restrict__ dotO,
    const _Float16* __restrict__ nw) {
  __shared__ __align__(16) unsigned char lds[32768 + BM * GI_STR * 2];

  const int t = threadIdx.x;
  const int srow = t >> 4;
  const int skc = t & 15;
  const int w = t >> 6;
  const int l = t & 63;
  const int lq = l >> 4;
  const int lr = l & 15;
  const int swm = (lr & 7) << 4;
  const int swz = (srow & 7) << 4;

  const f32x4 zz = {0.f, 0.f, 0.f, 0.f};
  f32x4 acc_r[4] = {zz, zz, zz, zz};
  f32x4 acc_z[4] = {zz, zz, zz, zz};
  f32x4 acc_nx[4] = {zz, zz, zz, zz};
  f32x4 acc_nh[4] = {zz, zz, zz, zz};

  if (blockIdx.x < EGRID) {
    // ================= edge GRU (f16 state) =================
    const int rb = blockIdx.x * BM;
    const int rowg = rb + srow;
    const int b = rowg / NEDGE;
    const int e = rowg - b * NEDGE;
    const int si = e / 31;
    const int m = e - si * 31;
    const int ob = (m < si) ? m : (m + 1);

    const uint4 v0 = *(const uint4*)(eh16 + rowg * 256 + skc * 8);
    const uint4 v1 = *(const uint4*)(eh16 + rowg * 256 + 128 + skc * 8);
    *(uint4*)(&lds[(srow * 512 + skc * 16) ^ swz]) = v0;
    *(uint4*)(&lds[(srow * 512 + 256 + skc * 16) ^ swz]) = v1;
    float pS = 0.f, pO = 0.f;
    {
      const _Float16* f0 = (const _Float16*)&v0;
      const _Float16* f1 = (const _Float16*)&v1;
      #pragma unroll
      for (int j = 0; j < 8; ++j) {
        const float a = (float)f0[j];
        const float bb = (float)f1[j];
        pS += a * wesb[skc * 8 + j] + bb * wesb[128 + skc * 8 + j];
        pO += a * weob[skc * 8 + j] + bb * weob[128 + skc * 8 + j];
      }
    }
    #pragma unroll
    for (int mm = 1; mm < 16; mm <<= 1) {
      pS += __shfl_xor(pS, mm, 16);
      pO += __shfl_xor(pO, mm, 16);
    }
    const float gs = sigf(dotS[b * NNODE + si] + pS);
    const float go = sigf(dotO[b * NNODE + ob] + pO);
    const _Float16 gsh = (_Float16)gs, goh = (_Float16)go;
    const _Float16* ns = nw + (b * NNODE + si) * 768;
    const _Float16* no_ = nw + (b * NNODE + ob) * 768;
    _Float16* giw = (_Float16*)(lds + GI_OFF) + srow * GI_STR;
    #pragma unroll
    for (int j = 0; j < 6; ++j) {
      const int c0 = skc * 8 + j * 128;
      const half8 a = *(const half8*)(ns + c0);
      const half8 bb = *(const half8*)(no_ + c0);
      half8 g;
      #pragma unroll
      for (int k = 0; k < 8; ++k) g[k] = gsh * a[k] + goh * bb[k];
      *(half8*)(giw + c0) = g;
    }
    __syncthreads();

    #pragma unroll
    for (int ksg = 0; ksg < 8; ++ksg) {
      half8 ah[4];
      #pragma unroll
      for (int rf = 0; rf < 4; ++rf)
        ah[rf] = *(const half8*)(&lds[((rf * 16 + lr) * 512 + ksg * 64 + lq * 16) ^ swm]);
      const int kk = 8 + ksg;
      const half8 br_ = *(const half8*)(wpe + (((0 * 16 + w) * 16 + kk) * 64 + l) * 8);
      const half8 bz_ = *(const half8*)(wpe + (((1 * 16 + w) * 16 + kk) * 64 + l) * 8);
      const half8 bn_ = *(const half8*)(wpe + (((2 * 16 + w) * 16 + kk) * 64 + l) * 8);
      #pragma unroll
      for (int rf = 0; rf < 4; ++rf)
        acc_r[rf] = __builtin_amdgcn_mfma_f32_16x16x32_f16(ah[rf], br_, acc_r[rf], 0, 0, 0);
      #pragma unroll
      for (int rf = 0; rf < 4; ++rf)
        acc_z[rf] = __builtin_amdgcn_mfma_f32_16x16x32_f16(ah[rf], bz_, acc_z[rf], 0, 0, 0);
      #pragma unroll
      for (int rf = 0; rf < 4; ++rf)
        acc_nh[rf] = __builtin_amdgcn_mfma_f32_16x16x32_f16(ah[rf], bn_, acc_nh[rf], 0, 0, 0);
    }

    const int col = w * 16 + lr;
    const float br = ebih[col] + ebhh[col];
    const float bz = ebih[256 + col] + ebhh[256 + col];
    const float bnx = ebih[512 + col];
    const float bnh = ebhh[512 + col];
    const _Float16* gir = (const _Float16*)(lds + GI_OFF);
    _Float16 sv[16];
    #pragma unroll
    for (int rf = 0; rf < 4; ++rf) {
      #pragma unroll
      for (int q = 0; q < 4; ++q) {
        const int rowl = rf * 16 + lq * 4 + q;
        const _Float16* gp = gir + rowl * GI_STR + col;
        const float r = sigf(acc_r[rf][q] + (float)gp[0] + br);
        const float z = sigf(acc_z[rf][q] + (float)gp[256] + bz);
        const float n = tanh_fast((float)gp[512] + bnx + r * (acc_nh[rf][q] + bnh));
        const float hv =
            (float)*(const _Float16*)(&lds[(rowl * 512 + col * 2) ^ ((rowl & 7) << 4)]);
        const float out = (1.0f - z) * n + z * hv;
        if constexpr (LAST) {
          ehf[(rb + rowl) * D_DIM + col] = out;
        } else {
          sv[rf * 4 + q] = (_Float16)out;
        }
      }
    }
    if constexpr (!LAST) {
      __syncthreads();
      #pragma unroll
      for (int rf = 0; rf < 4; ++rf) {
        #pragma unroll
        for (int q = 0; q < 4; ++q) {
          const int rowl = rf * 16 + lq * 4 + q;
          *(_Float16*)(&lds[(rowl * 512 + col * 2) ^ ((rowl & 7) << 4)]) = sv[rf * 4 + q];
        }
      }
      __syncthreads();
      #pragma unroll
      for (int p = 0; p < 2; ++p) {
        const int c = t + p * 1024;
        const int row = c >> 5;
        const int kc = c & 31;
        *(uint4*)(eh16 + (rb + row) * 256 + kc * 8) =
            *(const uint4*)(&lds[(row * 512 + kc * 16) ^ ((row & 7) << 4)]);
      }
    }
  } else {
    // ================= node GRU (f32 state, K-split h-first) =================
    const int rb = (blockIdx.x - EGRID) * BM;
    const int rowg = rb + srow;

    {
      float4 pre[4];
      #pragma unroll
      for (int i = 0; i < 4; ++i)
        pre[i] = *(const float4*)(nh + rowg * D_DIM + (i >> 1) * 128 + skc * 8 + (i & 1) * 4);
      #pragma unroll
      for (int c = 0; c < 2; ++c) {
        half8 hh8;
        const float* f1 = (const float*)&pre[c * 2];
        #pragma unroll
        for (int j = 0; j < 8; ++j) hh8[j] = (_Float16)f1[j];
        *(half8*)(&lds[(srow * 1024 + 512 + c * 256 + skc * 16) ^ swz]) = hh8;
      }
    }
    __syncthreads();

    #pragma unroll
    for (int ksg = 0; ksg < 8; ++ksg) {
      half8 ah[4];
      #pragma unroll
      for (int rf = 0; rf < 4; ++rf)
        ah[rf] = *(const half8*)(&lds[((rf * 16 + lr) * 1024 + 512 + ksg * 64 + lq * 16) ^ swm]);
      const int kk = 8 + ksg;
      const half8 br_ = *(const half8*)(wpn + (((0 * 16 + w) * 16 + kk) * 64 + l) * 8);
      const half8 bz_ = *(const half8*)(wpn + (((1 * 16 + w) * 16 + kk) * 64 + l) * 8);
      const half8 bn_ = *(const half8*)(wpn + (((2 * 16 + w) * 16 + kk) * 64 + l) * 8);
      #pragma unroll
      for (int rf = 0; rf < 4; ++rf)
        acc_r[rf] = __builtin_amdgcn_mfma_f32_16x16x32_f16(ah[rf], br_, acc_r[rf], 0, 0, 0);
      #pragma unroll
      for (int rf = 0; rf < 4; ++rf)
        acc_z[rf] = __builtin_amdgcn_mfma_f32_16x16x32_f16(ah[rf], bz_, acc_z[rf], 0, 0, 0);
      #pragma unroll
      for (int rf = 0; rf < 4; ++rf)
        acc_nh[rf] = __builtin_amdgcn_mfma_f32_16x16x32_f16(ah[rf], bn_, acc_nh[rf], 0, 0, 0);
    }

    #pragma unroll
    for (int c = 0; c < 2; ++c) {
      half8 hx;
      #pragma unroll
      for (int pq = 0; pq < 2; ++pq) {
        const float4 a = *(const float4*)(nmsg + rowg * D_DIM + c * 128 + skc * 8 + pq * 4);
        hx[pq * 4 + 0] = (_Float16)a.x; hx[pq * 4 + 1] = (_Float16)a.y;
        hx[pq * 4 + 2] = (_Float16)a.z; hx[pq * 4 + 3] = (_Float16)a.w;
      }
      *(half8*)(&lds[(srow * 1024 + 0 + c * 256 + skc * 16) ^ swz]) = hx;
    }
    __syncthreads();
    #pragma unroll
    for (int ksg = 0; ksg < 8; ++ksg) {
      half8 ah[4];
      #pragma unroll
      for (int rf = 0; rf < 4; ++rf)
        ah[rf] = *(const half8*)(&lds[((rf * 16 + lr) * 1024 + 0 + ksg * 64 + lq * 16) ^ swm]);
      const half8 br_ = *(const half8*)(wpn + (((0 * 16 + w) * 16 + ksg) * 64 + l) * 8);
      const half8 bz_ = *(const half8*)(wpn + (((1 * 16 + w) * 16 + ksg) * 64 + l) * 8);
      const half8 bn_ = *(const half8*)(wpn + (((2 * 16 + w) * 16 + ksg) * 64 + l) * 8);
      #pragma unroll
      for (int rf = 0; rf < 4; ++rf)
        acc_r[rf] = __builtin_amdgcn_mfma_f32_16x16x32_f16(ah[rf], br_, acc_r[rf], 0, 0, 0);
      #pragma unroll
      for (int rf = 0; rf < 4; ++rf)
        acc_z[rf] = __builtin_amdgcn_mfma_f32_16x16x32_f16(ah[rf], bz_, acc_z[rf], 0, 0, 0);
      #pragma unroll
      for (int rf = 0; rf < 4; ++rf)
        acc_nx[rf] = __builtin_amdgcn_mfma_f32_16x16x32_f16(ah[rf], bn_, acc_nx[rf], 0, 0, 0);
    }

    const int col = w * 16 + lr;
    const float br = nbih[col] + nbhh[col];
    const float bz = nbih[256 + col] + nbhh[256 + col];
    const float bnx = nbih[512 + col];
    const float bnh = nbhh[512 + col];
    #pragma unroll
    for (int rf = 0; rf < 4; ++rf) {
      #pragma unroll
      for (int q = 0; q < 4; ++q) {
        const int rowl = rf * 16 + lq * 4 + q;
        const float r = sigf(acc_r[rf][q] + br);
        const float z = sigf(acc_z[rf][q] + bz);
        const float n = tanh_fast(acc_nx[rf][q] + bnx + r * (acc_nh[rf][q] + bnh));
        const float hv = nh[(rb + rowl) * D_DIM + col];
        nh[(rb + rowl) * D_DIM + col] = (1.0f - z) * n + z * hv;
      }
    }
  }
}

// node_msg from eh16: gN inline; halved read traffic.
__global__ __launch_bounds__(256) void node_msg_kernel(
    const _Float16* __restrict__ eh16, const float* __restrict__ wnp,
    const float* __restrict__ dotA, float* __restrict__ nmsg) {
  __shared__ float sh[3][256];
  const int nr = blockIdx.x;
  const int b = nr >> 5;
  const int n = nr & 31;
  const int wv = threadIdx.x >> 6;
  const int l = threadIdx.x & 63;
  const int base = b * NEDGE;
  const float4 w1b = ((const float4*)(wnp + 256))[l];

  float4 acc = {0.f, 0.f, 0.f, 0.f};
  for (int k = wv; k < 62; k += 4) {
    int e, sub;
    if (k < 31) {
      e = base + n * 31 + k;
      sub = n;
    } else {
      int i = k - 31;
      const int ip = (i < n) ? i : (i + 1);
      e = base + ip * 31 + ((n < ip) ? n : (n - 1));
      sub = ip;
    }
    const half4v hv4 = ((const half4v*)(eh16 + e * 256))[l];
    float4 ev;
    ev.x = (float)hv4[0]; ev.y = (float)hv4[1];
    ev.z = (float)hv4[2]; ev.w = (float)hv4[3];
    float p = dot4(ev, w1b);
    #pragma unroll
    for (int mm = 32; mm > 0; mm >>= 1) p += __shfl_xor(p, mm, 64);
    const float gN = sigf(dotA[b * NNODE + sub] + p);
    acc.x += gN * ev.x; acc.y += gN * ev.y; acc.z += gN * ev.z; acc.w += gN * ev.w;
  }
  if (wv > 0) *(float4*)(&sh[wv - 1][l * 4]) = acc;
  __syncthreads();
  if (wv == 0) {
    #pragma unroll
    for (int v = 0; v < 3; ++v) {
      const float4 o = *(const float4*)(&sh[v][l * 4]);
      acc.x += o.x; acc.y += o.y; acc.z += o.z; acc.w += o.w;
    }
    *(float4*)(nmsg + nr * D_DIM + l * 4) = acc;
  }
}

extern "C" void kernel_launch(void* const* d_in, const int* in_sizes, int n_in,
                              void* d_out, int out_size, void* d_ws, size_t ws_size,
                              hipStream_t stream) {
  const float* node_latents = (const float*)d_in[0];
  const float* edge_latents = (const float*)d_in[1];
  const float* node_Wih = (const float*)d_in[2];
  const float* node_Whh = (const float*)d_in[3];
  const float* node_bih = (const float*)d_in[4];
  const float* node_bhh = (const float*)d_in[5];
  const float* edge_Wih = (const float*)d_in[6];
  const float* edge_Whh = (const float*)d_in[7];
  const float* edge_bih = (const float*)d_in[8];
  const float* edge_bhh = (const float*)d_in[9];
  const float* w_node_pool = (const float*)d_in[10];
  const float* w_edge_sub = (const float*)d_in[11];
  const float* w_edge_obj = (const float*)d_in[12];

  float* nh = (float*)d_out;
  float* eh = (float*)d_out + NODE_ROWS * D_DIM;

  const int WPLANE = 48 * 16 * 64 * 8;  // 768KB
  _Float16* ph_n = (_Float16*)d_ws;
  _Float16* ph_e = ph_n + WPLANE;
  _Float16* NW = ph_e + WPLANE;                    // 6 MB
  _Float16* eh16 = NW + NODE_ROWS * 768;           // 65 MB
  float* fw = (float*)(eh16 + (size_t)EDGE_ROWS * D_DIM);
  float* dotA = fw; fw += NODE_ROWS;
  float* dotS = fw; fw += NODE_ROWS;
  float* dotO = fw; fw += NODE_ROWS;
  float* node_msg = fw; fw += NODE_ROWS * D_DIM;   // total ~77 MB

  dim3 pg(48, 16);
  pack_w<<<pg, 64, 0, stream>>>(node_Wih, node_Whh, ph_n);
  pack_w<<<pg, 64, 0, stream>>>(edge_Wih, edge_Whh, ph_e);

  gru_init<<<EGRID + NGRID, 1024, 0, stream>>>(
      edge_latents, node_latents, eh16, nh, ph_e, ph_n,
      edge_bih, edge_bhh, node_bih, node_bhh);

  for (int it = 0; it < 3; ++it) {
    gru_nw<<<NGRID, 1024, 0, stream>>>(
        nh, ph_e, NW, w_node_pool, w_edge_sub, w_edge_obj, dotA, dotS, dotO);
    node_msg_kernel<<<NODE_ROWS, 256, 0, stream>>>(eh16, w_node_pool, dotA, node_msg);
    if (it < 2)
      gru_iter<false><<<EGRID + NGRID, 1024, 0, stream>>>(
          eh16, eh, nh, node_msg, ph_e, ph_n,
          edge_bih, edge_bhh, node_bih, node_bhh,
          w_edge_sub + 256, w_edge_obj + 256, dotS, dotO, NW);
    else
      gru_iter<true><<<EGRID + NGRID, 1024, 0, stream>>>(
          eh16, eh, nh, node_msg, ph_e, ph_n,
          edge_bih, edge_bhh, node_bih, node_bhh,
          w_edge_sub + 256, w_edge_obj + 256, dotS, dotO, NW);
  }
}

// Round 20
// 654.780 us; speedup vs baseline: 1.0932x; 1.0025x over previous
//
#include <hip/hip_runtime.h>

// ---------------------------------------------------------------------------
// Round 18: consolidation — R16 verbatim (best proven: 658us, absmax 0.0078).
//  R17's two changes both regressed and are reverted:
//   - init 2-tile pipeline: spilled (WRITE 67->174MB) — R7/R8 trap confirmed.
//   - nw+msg fusion: +8us/iter (queueing + redundant per-block dotA).
//  Falsified-lever ledger (do not retry): co-residency (R10/R12, register
//  wall), persistence (R5, L2 thrash), intra-block pipeline (R17, spill),
//  staging-chain cuts (R13/R14, not critical-path), extra fusion (R17).
//  Surviving structure: MFMA f16 GEMMs, NW hoist, R15 dispatch fusion,
//  f16 edge state (eh16), LDS hv carry, fused dot3.
// ---------------------------------------------------------------------------

#define D_DIM 256
#define NNODE 32
#define NEDGE 992
#define EDGE_ROWS (128 * NEDGE)   // 126976
#define NODE_ROWS (128 * NNODE)   // 4096
#define BM 64
#define EGRID (EDGE_ROWS / BM)    // 1984
#define NGRID (NODE_ROWS / BM)    // 64
#define GI_OFF 32768
#define GI_STR 776

typedef _Float16 half8 __attribute__((ext_vector_type(8)));
typedef _Float16 half4v __attribute__((ext_vector_type(4)));
typedef __attribute__((ext_vector_type(4))) float f32x4;

__device__ __forceinline__ float sigf(float x) { return 1.0f / (1.0f + __expf(-x)); }
__device__ __forceinline__ float tanh_fast(float x) { return 2.0f / (1.0f + __expf(-2.0f * x)) - 1.0f; }
__device__ __forceinline__ float dot4(float4 a, float4 b) { return a.x*b.x + a.y*b.y + a.z*b.z + a.w*b.w; }

__global__ __launch_bounds__(64) void pack_w(const float* __restrict__ Wih,
                                             const float* __restrict__ Whh,
                                             _Float16* __restrict__ ph) {
  const int ct = blockIdx.x;
  const int ks = blockIdx.y;
  const int l = threadIdx.x;
  const int col = ct * 16 + (l & 15);
  const int kb = ks * 32 + (l >> 4) * 8;
  const float* src = (kb < 256) ? (Wih + col * 256 + kb) : (Whh + col * 256 + (kb - 256));
  half8 v;
  #pragma unroll
  for (int j = 0; j < 8; ++j) v[j] = (_Float16)src[j];
  *(half8*)(ph + ((ct * 16 + ks) * 64 + l) * 8) = v;
}

// ---- INIT GRU (h=0): edge blocks write eh16; node blocks write f32 nh ----
__global__ __launch_bounds__(1024, 4) void gru_init(
    const float* __restrict__ xe, const float* __restrict__ xn,
    _Float16* __restrict__ eh16, float* __restrict__ hn,
    const _Float16* __restrict__ wpe, const _Float16* __restrict__ wpn,
    const float* __restrict__ ebih, const float* __restrict__ ebhh,
    const float* __restrict__ nbih, const float* __restrict__ nbhh) {
  __shared__ __align__(16) unsigned char lds[32768];
  const bool edge = blockIdx.x < EGRID;
  const int bx = edge ? blockIdx.x : (blockIdx.x - EGRID);
  const float* xsrc = edge ? xe : xn;
  const _Float16* wp = edge ? wpe : wpn;
  const float* bih = edge ? ebih : nbih;
  const float* bhh = edge ? ebhh : nbhh;

  const int t = threadIdx.x;
  const int rb = bx * BM;
  const int srow = t >> 4;
  const int skc = t & 15;
  const int w = t >> 6;
  const int l = t & 63;
  const int lq = l >> 4;
  const int lr = l & 15;
  const int swm = (lr & 7) << 4;
  const int swz = (srow & 7) << 4;
  const int rowg = rb + srow;

  #pragma unroll
  for (int c = 0; c < 2; ++c) {
    half8 hx;
    #pragma unroll
    for (int pq = 0; pq < 2; ++pq) {
      const float4 a = *(const float4*)(xsrc + rowg * D_DIM + c * 128 + skc * 8 + pq * 4);
      hx[pq * 4 + 0] = (_Float16)a.x; hx[pq * 4 + 1] = (_Float16)a.y;
      hx[pq * 4 + 2] = (_Float16)a.z; hx[pq * 4 + 3] = (_Float16)a.w;
    }
    *(half8*)(&lds[(srow * 512 + c * 256 + skc * 16) ^ swz]) = hx;
  }
  __syncthreads();

  const f32x4 zz = {0.f, 0.f, 0.f, 0.f};
  f32x4 acc_r[4] = {zz, zz, zz, zz};
  f32x4 acc_z[4] = {zz, zz, zz, zz};
  f32x4 acc_nx[4] = {zz, zz, zz, zz};

  #pragma unroll
  for (int ksg = 0; ksg < 8; ++ksg) {
    half8 ah[4];
    #pragma unroll
    for (int rf = 0; rf < 4; ++rf)
      ah[rf] = *(const half8*)(&lds[((rf * 16 + lr) * 512 + ksg * 64 + lq * 16) ^ swm]);
    const half8 br_ = *(const half8*)(wp + (((0 * 16 + w) * 16 + ksg) * 64 + l) * 8);
    const half8 bz_ = *(const half8*)(wp + (((1 * 16 + w) * 16 + ksg) * 64 + l) * 8);
    const half8 bn_ = *(const half8*)(wp + (((2 * 16 + w) * 16 + ksg) * 64 + l) * 8);
    #pragma unroll
    for (int rf = 0; rf < 4; ++rf)
      acc_r[rf] = __builtin_amdgcn_mfma_f32_16x16x32_f16(ah[rf], br_, acc_r[rf], 0, 0, 0);
    #pragma unroll
    for (int rf = 0; rf < 4; ++rf)
      acc_z[rf] = __builtin_amdgcn_mfma_f32_16x16x32_f16(ah[rf], bz_, acc_z[rf], 0, 0, 0);
    #pragma unroll
    for (int rf = 0; rf < 4; ++rf)
      acc_nx[rf] = __builtin_amdgcn_mfma_f32_16x16x32_f16(ah[rf], bn_, acc_nx[rf], 0, 0, 0);
  }

  const int col = w * 16 + lr;
  const float br = bih[col] + bhh[col];
  const float bz = bih[256 + col] + bhh[256 + col];
  const float bnx = bih[512 + col];
  const float bnh = bhh[512 + col];

  if (edge) {
    _Float16 sv[16];
    #pragma unroll
    for (int rf = 0; rf < 4; ++rf) {
      #pragma unroll
      for (int q = 0; q < 4; ++q) {
        const float r = sigf(acc_r[rf][q] + br);
        const float z = sigf(acc_z[rf][q] + bz);
        const float n = tanh_fast(acc_nx[rf][q] + bnx + r * bnh);
        sv[rf * 4 + q] = (_Float16)((1.0f - z) * n);
      }
    }
    __syncthreads();
    #pragma unroll
    for (int rf = 0; rf < 4; ++rf) {
      #pragma unroll
      for (int q = 0; q < 4; ++q) {
        const int rowl = rf * 16 + lq * 4 + q;
        *(_Float16*)(&lds[(rowl * 512 + col * 2) ^ ((rowl & 7) << 4)]) = sv[rf * 4 + q];
      }
    }
    __syncthreads();
    #pragma unroll
    for (int p = 0; p < 2; ++p) {
      const int c = t + p * 1024;
      const int row = c >> 5;
      const int kc = c & 31;
      *(uint4*)(eh16 + (rb + row) * 256 + kc * 8) =
          *(const uint4*)(&lds[(row * 512 + kc * 16) ^ ((row & 7) << 4)]);
    }
  } else {
    #pragma unroll
    for (int rf = 0; rf < 4; ++rf) {
      #pragma unroll
      for (int q = 0; q < 4; ++q) {
        const int rowl = rf * 16 + lq * 4 + q;
        const float r = sigf(acc_r[rf][q] + br);
        const float z = sigf(acc_z[rf][q] + bz);
        const float n = tanh_fast(acc_nx[rf][q] + bnx + r * bnh);
        hn[(rb + rowl) * D_DIM + col] = (1.0f - z) * n;
      }
    }
  }
}

// ---- NW = nh @ edge_WihT (f16 out) with dot3 fused into staging ----
__global__ __launch_bounds__(1024, 4) void gru_nw(
    const float* __restrict__ nh, const _Float16* __restrict__ wp,
    _Float16* __restrict__ nw,
    const float* __restrict__ wnp, const float* __restrict__ wes,
    const float* __restrict__ weo,
    float* __restrict__ dA, float* __restrict__ dS, float* __restrict__ dO) {
  __shared__ __align__(16) unsigned char lds[32768];
  const int t = threadIdx.x;
  const int rb = blockIdx.x * BM;
  const int srow = t >> 4;
  const int skc = t & 15;
  const int w = t >> 6;
  const int l = t & 63;
  const int lq = l >> 4;
  const int lr = l & 15;
  const int swm = (lr & 7) << 4;
  const int swz = (srow & 7) << 4;
  const int rowg = rb + srow;

  float4 xa[4];
  #pragma unroll
  for (int i = 0; i < 4; ++i)
    xa[i] = *(const float4*)(nh + rowg * D_DIM + (i >> 1) * 128 + skc * 8 + (i & 1) * 4);
  #pragma unroll
  for (int c = 0; c < 2; ++c) {
    half8 hx;
    const float* f0 = (const float*)&xa[c * 2];
    #pragma unroll
    for (int j = 0; j < 8; ++j) hx[j] = (_Float16)f0[j];
    *(half8*)(&lds[(srow * 512 + c * 256 + skc * 16) ^ swz]) = hx;
  }
  float p1 = 0.f, p2 = 0.f, p3 = 0.f;
  #pragma unroll
  for (int i = 0; i < 4; ++i) {
    const int k0 = (i >> 1) * 128 + skc * 8 + (i & 1) * 4;
    p1 += dot4(xa[i], *(const float4*)(wnp + k0));
    p2 += dot4(xa[i], *(const float4*)(wes + k0));
    p3 += dot4(xa[i], *(const float4*)(weo + k0));
  }
  #pragma unroll
  for (int mm = 1; mm < 16; mm <<= 1) {
    p1 += __shfl_xor(p1, mm, 16);
    p2 += __shfl_xor(p2, mm, 16);
    p3 += __shfl_xor(p3, mm, 16);
  }
  if (skc == 0) { dA[rowg] = p1; dS[rowg] = p2; dO[rowg] = p3; }
  __syncthreads();

  const f32x4 zz = {0.f, 0.f, 0.f, 0.f};
  f32x4 acc_r[4] = {zz, zz, zz, zz};
  f32x4 acc_z[4] = {zz, zz, zz, zz};
  f32x4 acc_nx[4] = {zz, zz, zz, zz};

  #pragma unroll
  for (int ksg = 0; ksg < 8; ++ksg) {
    half8 ah[4];
    #pragma unroll
    for (int rf = 0; rf < 4; ++rf)
      ah[rf] = *(const half8*)(&lds[((rf * 16 + lr) * 512 + ksg * 64 + lq * 16) ^ swm]);
    const half8 br_ = *(const half8*)(wp + (((0 * 16 + w) * 16 + ksg) * 64 + l) * 8);
    const half8 bz_ = *(const half8*)(wp + (((1 * 16 + w) * 16 + ksg) * 64 + l) * 8);
    const half8 bn_ = *(const half8*)(wp + (((2 * 16 + w) * 16 + ksg) * 64 + l) * 8);
    #pragma unroll
    for (int rf = 0; rf < 4; ++rf)
      acc_r[rf] = __builtin_amdgcn_mfma_f32_16x16x32_f16(ah[rf], br_, acc_r[rf], 0, 0, 0);
    #pragma unroll
    for (int rf = 0; rf < 4; ++rf)
      acc_z[rf] = __builtin_amdgcn_mfma_f32_16x16x32_f16(ah[rf], bz_, acc_z[rf], 0, 0, 0);
    #pragma unroll
    for (int rf = 0; rf < 4; ++rf)
      acc_nx[rf] = __builtin_amdgcn_mfma_f32_16x16x32_f16(ah[rf], bn_, acc_nx[rf], 0, 0, 0);
  }

  const int col = w * 16 + lr;
  #pragma unroll
  for (int rf = 0; rf < 4; ++rf) {
    #pragma unroll
    for (int q = 0; q < 4; ++q) {
      const int rowl = rf * 16 + lq * 4 + q;
      _Float16* np = nw + (rb + rowl) * 768 + col;
      np[0]   = (_Float16)acc_r[rf][q];
      np[256] = (_Float16)acc_z[rf][q];
      np[512] = (_Float16)acc_nx[rf][q];
    }
  }
}

// ---- fused iteration GRU: edge blocks [0,EGRID) on eh16, node blocks rest ----
template <bool LAST>
__global__ __launch_bounds__(1024, 4) void gru_iter(
    _Float16* __restrict__ eh16, float* __restrict__ ehf,
    float* __restrict__ nh, const float* __restrict__ nmsg,
    const _Float16* __restrict__ wpe, const _Float16* __restrict__ wpn,
    const float* __restrict__ ebih, const float* __restrict__ ebhh,
    const float* __restrict__ nbih, const float* __restrict__ nbhh,
    const float* __restrict__ wesb, const float* __restrict__ weob,
    const float* __restrict__ dotS, const float* __restrict__ dotO,
    const _Float16* __restrict__ nw) {
  __shared__ __align__(16) unsigned char lds[32768 + BM * GI_STR * 2];

  const int t = threadIdx.x;
  const int srow = t >> 4;
  const int skc = t & 15;
  const int w = t >> 6;
  const int l = t & 63;
  const int lq = l >> 4;
  const int lr = l & 15;
  const int swm = (lr & 7) << 4;
  const int swz = (srow & 7) << 4;

  const f32x4 zz = {0.f, 0.f, 0.f, 0.f};
  f32x4 acc_r[4] = {zz, zz, zz, zz};
  f32x4 acc_z[4] = {zz, zz, zz, zz};
  f32x4 acc_nx[4] = {zz, zz, zz, zz};
  f32x4 acc_nh[4] = {zz, zz, zz, zz};

  if (blockIdx.x < EGRID) {
    // ================= edge GRU (f16 state) =================
    const int rb = blockIdx.x * BM;
    const int rowg = rb + srow;
    const int b = rowg / NEDGE;
    const int e = rowg - b * NEDGE;
    const int si = e / 31;
    const int m = e - si * 31;
    const int ob = (m < si) ? m : (m + 1);

    const uint4 v0 = *(const uint4*)(eh16 + rowg * 256 + skc * 8);
    const uint4 v1 = *(const uint4*)(eh16 + rowg * 256 + 128 + skc * 8);
    *(uint4*)(&lds[(srow * 512 + skc * 16) ^ swz]) = v0;
    *(uint4*)(&lds[(srow * 512 + 256 + skc * 16) ^ swz]) = v1;
    float pS = 0.f, pO = 0.f;
    {
      const _Float16* f0 = (const _Float16*)&v0;
      const _Float16* f1 = (const _Float16*)&v1;
      #pragma unroll
      for (int j = 0; j < 8; ++j) {
        const float a = (float)f0[j];
        const float bb = (float)f1[j];
        pS += a * wesb[skc * 8 + j] + bb * wesb[128 + skc * 8 + j];
        pO += a * weob[skc * 8 + j] + bb * weob[128 + skc * 8 + j];
      }
    }
    #pragma unroll
    for (int mm = 1; mm < 16; mm <<= 1) {
      pS += __shfl_xor(pS, mm, 16);
      pO += __shfl_xor(pO, mm, 16);
    }
    const float gs = sigf(dotS[b * NNODE + si] + pS);
    const float go = sigf(dotO[b * NNODE + ob] + pO);
    const _Float16 gsh = (_Float16)gs, goh = (_Float16)go;
    const _Float16* ns = nw + (b * NNODE + si) * 768;
    const _Float16* no_ = nw + (b * NNODE + ob) * 768;
    _Float16* giw = (_Float16*)(lds + GI_OFF) + srow * GI_STR;
    #pragma unroll
    for (int j = 0; j < 6; ++j) {
      const int c0 = skc * 8 + j * 128;
      const half8 a = *(const half8*)(ns + c0);
      const half8 bb = *(const half8*)(no_ + c0);
      half8 g;
      #pragma unroll
      for (int k = 0; k < 8; ++k) g[k] = gsh * a[k] + goh * bb[k];
      *(half8*)(giw + c0) = g;
    }
    __syncthreads();

    #pragma unroll
    for (int ksg = 0; ksg < 8; ++ksg) {
      half8 ah[4];
      #pragma unroll
      for (int rf = 0; rf < 4; ++rf)
        ah[rf] = *(const half8*)(&lds[((rf * 16 + lr) * 512 + ksg * 64 + lq * 16) ^ swm]);
      const int kk = 8 + ksg;
      const half8 br_ = *(const half8*)(wpe + (((0 * 16 + w) * 16 + kk) * 64 + l) * 8);
      const half8 bz_ = *(const half8*)(wpe + (((1 * 16 + w) * 16 + kk) * 64 + l) * 8);
      const half8 bn_ = *(const half8*)(wpe + (((2 * 16 + w) * 16 + kk) * 64 + l) * 8);
      #pragma unroll
      for (int rf = 0; rf < 4; ++rf)
        acc_r[rf] = __builtin_amdgcn_mfma_f32_16x16x32_f16(ah[rf], br_, acc_r[rf], 0, 0, 0);
      #pragma unroll
      for (int rf = 0; rf < 4; ++rf)
        acc_z[rf] = __builtin_amdgcn_mfma_f32_16x16x32_f16(ah[rf], bz_, acc_z[rf], 0, 0, 0);
      #pragma unroll
      for (int rf = 0; rf < 4; ++rf)
        acc_nh[rf] = __builtin_amdgcn_mfma_f32_16x16x32_f16(ah[rf], bn_, acc_nh[rf], 0, 0, 0);
    }

    const int col = w * 16 + lr;
    const float br = ebih[col] + ebhh[col];
    const float bz = ebih[256 + col] + ebhh[256 + col];
    const float bnx = ebih[512 + col];
    const float bnh = ebhh[512 + col];
    const _Float16* gir = (const _Float16*)(lds + GI_OFF);
    _Float16 sv[16];
    #pragma unroll
    for (int rf = 0; rf < 4; ++rf) {
      #pragma unroll
      for (int q = 0; q < 4; ++q) {
        const int rowl = rf * 16 + lq * 4 + q;
        const _Float16* gp = gir + rowl * GI_STR + col;
        const float r = sigf(acc_r[rf][q] + (float)gp[0] + br);
        const float z = sigf(acc_z[rf][q] + (float)gp[256] + bz);
        const float n = tanh_fast((float)gp[512] + bnx + r * (acc_nh[rf][q] + bnh));
        const float hv =
            (float)*(const _Float16*)(&lds[(rowl * 512 + col * 2) ^ ((rowl & 7) << 4)]);
        const float out = (1.0f - z) * n + z * hv;
        if constexpr (LAST) {
          ehf[(rb + rowl) * D_DIM + col] = out;
        } else {
          sv[rf * 4 + q] = (_Float16)out;
        }
      }
    }
    if constexpr (!LAST) {
      __syncthreads();
      #pragma unroll
      for (int rf = 0; rf < 4; ++rf) {
        #pragma unroll
        for (int q = 0; q < 4; ++q) {
          const int rowl = rf * 16 + lq * 4 + q;
          *(_Float16*)(&lds[(rowl * 512 + col * 2) ^ ((rowl & 7) << 4)]) = sv[rf * 4 + q];
        }
      }
      __syncthreads();
      #pragma unroll
      for (int p = 0; p < 2; ++p) {
        const int c = t + p * 1024;
        const int row = c >> 5;
        const int kc = c & 31;
        *(uint4*)(eh16 + (rb + row) * 256 + kc * 8) =
            *(const uint4*)(&lds[(row * 512 + kc * 16) ^ ((row & 7) << 4)]);
      }
    }
  } else {
    // ================= node GRU (f32 state, K-split h-first) =================
    const int rb = (blockIdx.x - EGRID) * BM;
    const int rowg = rb + srow;

    {
      float4 pre[4];
      #pragma unroll
      for (int i = 0; i < 4; ++i)
        pre[i] = *(const float4*)(nh + rowg * D_DIM + (i >> 1) * 128 + skc * 8 + (i & 1) * 4);
      #pragma unroll
      for (int c = 0; c < 2; ++c) {
        half8 hh8;
        const float* f1 = (const float*)&pre[c * 2];
        #pragma unroll
        for (int j = 0; j < 8; ++j) hh8[j] = (_Float16)f1[j];
        *(half8*)(&lds[(srow * 1024 + 512 + c * 256 + skc * 16) ^ swz]) = hh8;
      }
    }
    __syncthreads();

    #pragma unroll
    for (int ksg = 0; ksg < 8; ++ksg) {
      half8 ah[4];
      #pragma unroll
      for (int rf = 0; rf < 4; ++rf)
        ah[rf] = *(const half8*)(&lds[((rf * 16 + lr) * 1024 + 512 + ksg * 64 + lq * 16) ^ swm]);
      const int kk = 8 + ksg;
      const half8 br_ = *(const half8*)(wpn + (((0 * 16 + w) * 16 + kk) * 64 + l) * 8);
      const half8 bz_ = *(const half8*)(wpn + (((1 * 16 + w) * 16 + kk) * 64 + l) * 8);
      const half8 bn_ = *(const half8*)(wpn + (((2 * 16 + w) * 16 + kk) * 64 + l) * 8);
      #pragma unroll
      for (int rf = 0; rf < 4; ++rf)
        acc_r[rf] = __builtin_amdgcn_mfma_f32_16x16x32_f16(ah[rf], br_, acc_r[rf], 0, 0, 0);
      #pragma unroll
      for (int rf = 0; rf < 4; ++rf)
        acc_z[rf] = __builtin_amdgcn_mfma_f32_16x16x32_f16(ah[rf], bz_, acc_z[rf], 0, 0, 0);
      #pragma unroll
      for (int rf = 0; rf < 4; ++rf)
        acc_nh[rf] = __builtin_amdgcn_mfma_f32_16x16x32_f16(ah[rf], bn_, acc_nh[rf], 0, 0, 0);
    }

    #pragma unroll
    for (int c = 0; c < 2; ++c) {
      half8 hx;
      #pragma unroll
      for (int pq = 0; pq < 2; ++pq) {
        const float4 a = *(const float4*)(nmsg + rowg * D_DIM + c * 128 + skc * 8 + pq * 4);
        hx[pq * 4 + 0] = (_Float16)a.x; hx[pq * 4 + 1] = (_Float16)a.y;
        hx[pq * 4 + 2] = (_Float16)a.z; hx[pq * 4 + 3] = (_Float16)a.w;
      }
      *(half8*)(&lds[(srow * 1024 + 0 + c * 256 + skc * 16) ^ swz]) = hx;
    }
    __syncthreads();
    #pragma unroll
    for (int ksg = 0; ksg < 8; ++ksg) {
      half8 ah[4];
      #pragma unroll
      for (int rf = 0; rf < 4; ++rf)
        ah[rf] = *(const half8*)(&lds[((rf * 16 + lr) * 1024 + 0 + ksg * 64 + lq * 16) ^ swm]);
      const half8 br_ = *(const half8*)(wpn + (((0 * 16 + w) * 16 + ksg) * 64 + l) * 8);
      const half8 bz_ = *(const half8*)(wpn + (((1 * 16 + w) * 16 + ksg) * 64 + l) * 8);
      const half8 bn_ = *(const half8*)(wpn + (((2 * 16 + w) * 16 + ksg) * 64 + l) * 8);
      #pragma unroll
      for (int rf = 0; rf < 4; ++rf)
        acc_r[rf] = __builtin_amdgcn_mfma_f32_16x16x32_f16(ah[rf], br_, acc_r[rf], 0, 0, 0);
      #pragma unroll
      for (int rf = 0; rf < 4; ++rf)
        acc_z[rf] = __builtin_amdgcn_mfma_f32_16x16x32_f16(ah[rf], bz_, acc_z[rf], 0, 0, 0);
      #pragma unroll
      for (int rf = 0; rf < 4; ++rf)
        acc_nx[rf] = __builtin_amdgcn_mfma_f32_16x16x32_f16(ah[rf], bn_, acc_nx[rf], 0, 0, 0);
    }

    const int col = w * 16 + lr;
    const float br = nbih[col] + nbhh[col];
    const float bz = nbih[256 + col] + nbhh[256 + col];
    const float bnx = nbih[512 + col];
    const float bnh = nbhh[512 + col];
    #pragma unroll
    for (int rf = 0; rf < 4; ++rf) {
      #pragma unroll
      for (int q = 0; q < 4; ++q) {
        const int rowl = rf * 16 + lq * 4 + q;
        const float r = sigf(acc_r[rf][q] + br);
        const float z = sigf(acc_z[rf][q] + bz);
        const float n = tanh_fast(acc_nx[rf][q] + bnx + r * (acc_nh[rf][q] + bnh));
        const float hv = nh[(rb + rowl) * D_DIM + col];
        nh[(rb + rowl) * D_DIM + col] = (1.0f - z) * n + z * hv;
      }
    }
  }
}

// node_msg from eh16: gN inline; halved read traffic.
__global__ __launch_bounds__(256) void node_msg_kernel(
    const _Float16* __restrict__ eh16, const float* __restrict__ wnp,
    const float* __restrict__ dotA, float* __restrict__ nmsg) {
  __shared__ float sh[3][256];
  const int nr = blockIdx.x;
  const int b = nr >> 5;
  const int n = nr & 31;
  const int wv = threadIdx.x >> 6;
  const int l = threadIdx.x & 63;
  const int base = b * NEDGE;
  const float4 w1b = ((const float4*)(wnp + 256))[l];

  float4 acc = {0.f, 0.f, 0.f, 0.f};
  for (int k = wv; k < 62; k += 4) {
    int e, sub;
    if (k < 31) {
      e = base + n * 31 + k;
      sub = n;
    } else {
      int i = k - 31;
      const int ip = (i < n) ? i : (i + 1);
      e = base + ip * 31 + ((n < ip) ? n : (n - 1));
      sub = ip;
    }
    const half4v hv4 = ((const half4v*)(eh16 + e * 256))[l];
    float4 ev;
    ev.x = (float)hv4[0]; ev.y = (float)hv4[1];
    ev.z = (float)hv4[2]; ev.w = (float)hv4[3];
    float p = dot4(ev, w1b);
    #pragma unroll
    for (int mm = 32; mm > 0; mm >>= 1) p += __shfl_xor(p, mm, 64);
    const float gN = sigf(dotA[b * NNODE + sub] + p);
    acc.x += gN * ev.x; acc.y += gN * ev.y; acc.z += gN * ev.z; acc.w += gN * ev.w;
  }
  if (wv > 0) *(float4*)(&sh[wv - 1][l * 4]) = acc;
  __syncthreads();
  if (wv == 0) {
    #pragma unroll
    for (int v = 0; v < 3; ++v) {
      const float4 o = *(const float4*)(&sh[v][l * 4]);
      acc.x += o.x; acc.y += o.y; acc.z += o.z; acc.w += o.w;
    }
    *(float4*)(nmsg + nr * D_DIM + l * 4) = acc;
  }
}

extern "C" void kernel_launch(void* const* d_in, const int* in_sizes, int n_in,
                              void* d_out, int out_size, void* d_ws, size_t ws_size,
                              hipStream_t stream) {
  const float* node_latents = (const float*)d_in[0];
  const float* edge_latents = (const float*)d_in[1];
  const float* node_Wih = (const float*)d_in[2];
  const float* node_Whh = (const float*)d_in[3];
  const float* node_bih = (const float*)d_in[4];
  const float* node_bhh = (const float*)d_in[5];
  const float* edge_Wih = (const float*)d_in[6];
  const float* edge_Whh = (const float*)d_in[7];
  const float* edge_bih = (const float*)d_in[8];
  const float* edge_bhh = (const float*)d_in[9];
  const float* w_node_pool = (const float*)d_in[10];
  const float* w_edge_sub = (const float*)d_in[11];
  const float* w_edge_obj = (const float*)d_in[12];

  float* nh = (float*)d_out;
  float* eh = (float*)d_out + NODE_ROWS * D_DIM;

  const int WPLANE = 48 * 16 * 64 * 8;  // 768KB
  _Float16* ph_n = (_Float16*)d_ws;
  _Float16* ph_e = ph_n + WPLANE;
  _Float16* NW = ph_e + WPLANE;                    // 6 MB
  _Float16* eh16 = NW + NODE_ROWS * 768;           // 65 MB
  float* fw = (float*)(eh16 + (size_t)EDGE_ROWS * D_DIM);
  float* dotA = fw; fw += NODE_ROWS;
  float* dotS = fw; fw += NODE_ROWS;
  float* dotO = fw; fw += NODE_ROWS;
  float* node_msg = fw; fw += NODE_ROWS * D_DIM;   // total ~77 MB

  dim3 pg(48, 16);
  pack_w<<<pg, 64, 0, stream>>>(node_Wih, node_Whh, ph_n);
  pack_w<<<pg, 64, 0, stream>>>(edge_Wih, edge_Whh, ph_e);

  gru_init<<<EGRID + NGRID, 1024, 0, stream>>>(
      edge_latents, node_latents, eh16, nh, ph_e, ph_n,
      edge_bih, edge_bhh, node_bih, node_bhh);

  for (int it = 0; it < 3; ++it) {
    gru_nw<<<NGRID, 1024, 0, stream>>>(
        nh, ph_e, NW, w_node_pool, w_edge_sub, w_edge_obj, dotA, dotS, dotO);
    node_msg_kernel<<<NODE_ROWS, 256, 0, stream>>>(eh16, w_node_pool, dotA, node_msg);
    if (it < 2)
      gru_iter<false><<<EGRID + NGRID, 1024, 0, stream>>>(
          eh16, eh, nh, node_msg, ph_e, ph_n,
          edge_bih, edge_bhh, node_bih, node_bhh,
          w_edge_sub + 256, w_edge_obj + 256, dotS, dotO, NW);
    else
      gru_iter<true><<<EGRID + NGRID, 1024, 0, stream>>>(
          eh16, eh, nh, node_msg, ph_e, ph_n,
          edge_bih, edge_bhh, node_bih, node_bhh,
          w_edge_sub + 256, w_edge_obj + 256, dotS, dotO, NW);
  }
}

// Round 22
// 643.450 us; speedup vs baseline: 1.1124x; 1.0176x over previous
//
#include <hip/hip_runtime.h>

// ---------------------------------------------------------------------------
// Round 21: R20 with the NW/dots RACE FIXED via ping-pong generations.
//  R20 bug: gru_iter's node-tail wrote NW/dotS/dotO into the SAME buffers its
//  own edge blocks were reading -> race -> absmax 2.0. Now two generations:
//    init tail -> gen0; iter0 reads gen0, writes gen1; iter1 reads gen1,
//    writes gen0; iter2 (LAST) reads gen0, no tail.
//  Everything else = R20 (= R16 base + gru_nw eliminated into node-tails).
// ---------------------------------------------------------------------------

#define D_DIM 256
#define NNODE 32
#define NEDGE 992
#define EDGE_ROWS (128 * NEDGE)   // 126976
#define NODE_ROWS (128 * NNODE)   // 4096
#define BM 64
#define EGRID (EDGE_ROWS / BM)    // 1984
#define NGRID (NODE_ROWS / BM)    // 64
#define GI_OFF 32768
#define GI_STR 776
#define NT_OFF 65536              // iter node-tail f16 region (32KB)

typedef _Float16 half8 __attribute__((ext_vector_type(8)));
typedef _Float16 half4v __attribute__((ext_vector_type(4)));
typedef __attribute__((ext_vector_type(4))) float f32x4;

__device__ __forceinline__ float sigf(float x) { return 1.0f / (1.0f + __expf(-x)); }
__device__ __forceinline__ float tanh_fast(float x) { return 2.0f / (1.0f + __expf(-2.0f * x)) - 1.0f; }
__device__ __forceinline__ float dot4(float4 a, float4 b) { return a.x*b.x + a.y*b.y + a.z*b.z + a.w*b.w; }

__global__ __launch_bounds__(64) void pack_w(const float* __restrict__ Wih,
                                             const float* __restrict__ Whh,
                                             _Float16* __restrict__ ph) {
  const int ct = blockIdx.x;
  const int ks = blockIdx.y;
  const int l = threadIdx.x;
  const int col = ct * 16 + (l & 15);
  const int kb = ks * 32 + (l >> 4) * 8;
  const float* src = (kb < 256) ? (Wih + col * 256 + kb) : (Whh + col * 256 + (kb - 256));
  half8 v;
  #pragma unroll
  for (int j = 0; j < 8; ++j) v[j] = (_Float16)src[j];
  *(half8*)(ph + ((ct * 16 + ks) * 64 + l) * 8) = v;
}

// Node tail: from the f16 nh image in `reg` (stride-512, XOR-swizzled),
// compute dot3 and the NW GEMM. Caller must barrier AFTER writing the image.
__device__ __forceinline__ void nw_tail(
    unsigned char* reg, int rb, int t,
    const _Float16* __restrict__ wpe,
    const float* __restrict__ wnp, const float* __restrict__ wes,
    const float* __restrict__ weo,
    float* __restrict__ dA, float* __restrict__ dS, float* __restrict__ dO,
    _Float16* __restrict__ nw) {
  const int srow = t >> 4;
  const int skc = t & 15;
  const int w = t >> 6;
  const int l = t & 63;
  const int lq = l >> 4;
  const int lr = l & 15;
  const int swm = (lr & 7) << 4;
  const int swz = (srow & 7) << 4;
  const int rowg = rb + srow;

  // ---- dot3 from the f16 image ----
  float p1 = 0.f, p2 = 0.f, p3 = 0.f;
  #pragma unroll
  for (int c = 0; c < 2; ++c) {
    const uint4 v = *(const uint4*)(&reg[(srow * 512 + c * 256 + skc * 16) ^ swz]);
    const _Float16* f = (const _Float16*)&v;
    #pragma unroll
    for (int j = 0; j < 8; ++j) {
      const float a = (float)f[j];
      const int cc = c * 128 + skc * 8 + j;
      p1 += a * wnp[cc];
      p2 += a * wes[cc];
      p3 += a * weo[cc];
    }
  }
  #pragma unroll
  for (int mm = 1; mm < 16; mm <<= 1) {
    p1 += __shfl_xor(p1, mm, 16);
    p2 += __shfl_xor(p2, mm, 16);
    p3 += __shfl_xor(p3, mm, 16);
  }
  if (skc == 0) { dA[rowg] = p1; dS[rowg] = p2; dO[rowg] = p3; }

  // ---- NW = nh @ edge_WihT (x-half of wpe) ----
  const f32x4 zz = {0.f, 0.f, 0.f, 0.f};
  f32x4 ar[4] = {zz, zz, zz, zz};
  f32x4 az[4] = {zz, zz, zz, zz};
  f32x4 an[4] = {zz, zz, zz, zz};
  #pragma unroll
  for (int ksg = 0; ksg < 8; ++ksg) {
    half8 ah[4];
    #pragma unroll
    for (int rf = 0; rf < 4; ++rf)
      ah[rf] = *(const half8*)(&reg[((rf * 16 + lr) * 512 + ksg * 64 + lq * 16) ^ swm]);
    const half8 br_ = *(const half8*)(wpe + (((0 * 16 + w) * 16 + ksg) * 64 + l) * 8);
    const half8 bz_ = *(const half8*)(wpe + (((1 * 16 + w) * 16 + ksg) * 64 + l) * 8);
    const half8 bn_ = *(const half8*)(wpe + (((2 * 16 + w) * 16 + ksg) * 64 + l) * 8);
    #pragma unroll
    for (int rf = 0; rf < 4; ++rf)
      ar[rf] = __builtin_amdgcn_mfma_f32_16x16x32_f16(ah[rf], br_, ar[rf], 0, 0, 0);
    #pragma unroll
    for (int rf = 0; rf < 4; ++rf)
      az[rf] = __builtin_amdgcn_mfma_f32_16x16x32_f16(ah[rf], bz_, az[rf], 0, 0, 0);
    #pragma unroll
    for (int rf = 0; rf < 4; ++rf)
      an[rf] = __builtin_amdgcn_mfma_f32_16x16x32_f16(ah[rf], bn_, an[rf], 0, 0, 0);
  }
  const int col = w * 16 + lr;
  #pragma unroll
  for (int rf = 0; rf < 4; ++rf) {
    #pragma unroll
    for (int q = 0; q < 4; ++q) {
      const int rowl = rf * 16 + lq * 4 + q;
      _Float16* np = nw + (rb + rowl) * 768 + col;
      np[0]   = (_Float16)ar[rf][q];
      np[256] = (_Float16)az[rf][q];
      np[512] = (_Float16)an[rf][q];
    }
  }
}

// ---- INIT GRU (h=0): node blocks [0,NGRID) (+tail -> gen0), edge blocks rest ----
__global__ __launch_bounds__(1024, 4) void gru_init(
    const float* __restrict__ xe, const float* __restrict__ xn,
    _Float16* __restrict__ eh16, float* __restrict__ hn,
    const _Float16* __restrict__ wpe, const _Float16* __restrict__ wpn,
    const float* __restrict__ ebih, const float* __restrict__ ebhh,
    const float* __restrict__ nbih, const float* __restrict__ nbhh,
    const float* __restrict__ wnp, const float* __restrict__ wes,
    const float* __restrict__ weo,
    float* __restrict__ dA, float* __restrict__ dS, float* __restrict__ dO,
    _Float16* __restrict__ nw) {
  __shared__ __align__(16) unsigned char lds[32768];
  const bool node = blockIdx.x < NGRID;
  const int bx = node ? blockIdx.x : (blockIdx.x - NGRID);
  const float* xsrc = node ? xn : xe;
  const _Float16* wp = node ? wpn : wpe;
  const float* bih = node ? nbih : ebih;
  const float* bhh = node ? nbhh : ebhh;

  const int t = threadIdx.x;
  const int rb = bx * BM;
  const int srow = t >> 4;
  const int skc = t & 15;
  const int w = t >> 6;
  const int l = t & 63;
  const int lq = l >> 4;
  const int lr = l & 15;
  const int swm = (lr & 7) << 4;
  const int swz = (srow & 7) << 4;
  const int rowg = rb + srow;

  #pragma unroll
  for (int c = 0; c < 2; ++c) {
    half8 hx;
    #pragma unroll
    for (int pq = 0; pq < 2; ++pq) {
      const float4 a = *(const float4*)(xsrc + rowg * D_DIM + c * 128 + skc * 8 + pq * 4);
      hx[pq * 4 + 0] = (_Float16)a.x; hx[pq * 4 + 1] = (_Float16)a.y;
      hx[pq * 4 + 2] = (_Float16)a.z; hx[pq * 4 + 3] = (_Float16)a.w;
    }
    *(half8*)(&lds[(srow * 512 + c * 256 + skc * 16) ^ swz]) = hx;
  }
  __syncthreads();

  const f32x4 zz = {0.f, 0.f, 0.f, 0.f};
  f32x4 acc_r[4] = {zz, zz, zz, zz};
  f32x4 acc_z[4] = {zz, zz, zz, zz};
  f32x4 acc_nx[4] = {zz, zz, zz, zz};

  #pragma unroll
  for (int ksg = 0; ksg < 8; ++ksg) {
    half8 ah[4];
    #pragma unroll
    for (int rf = 0; rf < 4; ++rf)
      ah[rf] = *(const half8*)(&lds[((rf * 16 + lr) * 512 + ksg * 64 + lq * 16) ^ swm]);
    const half8 br_ = *(const half8*)(wp + (((0 * 16 + w) * 16 + ksg) * 64 + l) * 8);
    const half8 bz_ = *(const half8*)(wp + (((1 * 16 + w) * 16 + ksg) * 64 + l) * 8);
    const half8 bn_ = *(const half8*)(wp + (((2 * 16 + w) * 16 + ksg) * 64 + l) * 8);
    #pragma unroll
    for (int rf = 0; rf < 4; ++rf)
      acc_r[rf] = __builtin_amdgcn_mfma_f32_16x16x32_f16(ah[rf], br_, acc_r[rf], 0, 0, 0);
    #pragma unroll
    for (int rf = 0; rf < 4; ++rf)
      acc_z[rf] = __builtin_amdgcn_mfma_f32_16x16x32_f16(ah[rf], bz_, acc_z[rf], 0, 0, 0);
    #pragma unroll
    for (int rf = 0; rf < 4; ++rf)
      acc_nx[rf] = __builtin_amdgcn_mfma_f32_16x16x32_f16(ah[rf], bn_, acc_nx[rf], 0, 0, 0);
  }

  const int col = w * 16 + lr;
  const float br = bih[col] + bhh[col];
  const float bz = bih[256 + col] + bhh[256 + col];
  const float bnx = bih[512 + col];
  const float bnh = bhh[512 + col];

  _Float16 sv[16];
  #pragma unroll
  for (int rf = 0; rf < 4; ++rf) {
    #pragma unroll
    for (int q = 0; q < 4; ++q) {
      const float r = sigf(acc_r[rf][q] + br);
      const float z = sigf(acc_z[rf][q] + bz);
      const float n = tanh_fast(acc_nx[rf][q] + bnx + r * bnh);
      const float out = (1.0f - z) * n;
      sv[rf * 4 + q] = (_Float16)out;
      if (node) {
        const int rowl = rf * 16 + lq * 4 + q;
        hn[(rb + rowl) * D_DIM + col] = out;
      }
    }
  }
  __syncthreads();  // staging region reads done; safe to overwrite
  #pragma unroll
  for (int rf = 0; rf < 4; ++rf) {
    #pragma unroll
    for (int q = 0; q < 4; ++q) {
      const int rowl = rf * 16 + lq * 4 + q;
      *(_Float16*)(&lds[(rowl * 512 + col * 2) ^ ((rowl & 7) << 4)]) = sv[rf * 4 + q];
    }
  }
  __syncthreads();
  if (node) {
    nw_tail(lds, rb, t, wpe, wnp, wes, weo, dA, dS, dO, nw);
  } else {
    #pragma unroll
    for (int p = 0; p < 2; ++p) {
      const int c = t + p * 1024;
      const int row = c >> 5;
      const int kc = c & 31;
      *(uint4*)(eh16 + (rb + row) * 256 + kc * 8) =
          *(const uint4*)(&lds[(row * 512 + kc * 16) ^ ((row & 7) << 4)]);
    }
  }
}

// ---- fused iteration: node blocks [0,NGRID) (+tail -> OTHER gen), edge rest ----
template <bool LAST>
__global__ __launch_bounds__(1024, 4) void gru_iter(
    _Float16* __restrict__ eh16, float* __restrict__ ehf,
    float* __restrict__ nh, const float* __restrict__ nmsg,
    const _Float16* __restrict__ wpe, const _Float16* __restrict__ wpn,
    const float* __restrict__ ebih, const float* __restrict__ ebhh,
    const float* __restrict__ nbih, const float* __restrict__ nbhh,
    const float* __restrict__ wesb, const float* __restrict__ weob,
    const float* __restrict__ dotS, const float* __restrict__ dotO,
    const _Float16* __restrict__ nw,
    const float* __restrict__ wnp, const float* __restrict__ wes,
    const float* __restrict__ weo,
    float* __restrict__ dAo, float* __restrict__ dSo, float* __restrict__ dOo,
    _Float16* __restrict__ nwo) {
  __shared__ __align__(16) unsigned char lds[32768 + BM * GI_STR * 2];  // 132KB

  const int t = threadIdx.x;
  const int srow = t >> 4;
  const int skc = t & 15;
  const int w = t >> 6;
  const int l = t & 63;
  const int lq = l >> 4;
  const int lr = l & 15;
  const int swm = (lr & 7) << 4;
  const int swz = (srow & 7) << 4;

  const f32x4 zz = {0.f, 0.f, 0.f, 0.f};
  f32x4 acc_r[4] = {zz, zz, zz, zz};
  f32x4 acc_z[4] = {zz, zz, zz, zz};
  f32x4 acc_nx[4] = {zz, zz, zz, zz};
  f32x4 acc_nh[4] = {zz, zz, zz, zz};

  if (blockIdx.x >= NGRID) {
    // ================= edge GRU (f16 state), reads gen-IN =================
    const int rb = (blockIdx.x - NGRID) * BM;
    const int rowg = rb + srow;
    const int b = rowg / NEDGE;
    const int e = rowg - b * NEDGE;
    const int si = e / 31;
    const int m = e - si * 31;
    const int ob = (m < si) ? m : (m + 1);

    const uint4 v0 = *(const uint4*)(eh16 + rowg * 256 + skc * 8);
    const uint4 v1 = *(const uint4*)(eh16 + rowg * 256 + 128 + skc * 8);
    *(uint4*)(&lds[(srow * 512 + skc * 16) ^ swz]) = v0;
    *(uint4*)(&lds[(srow * 512 + 256 + skc * 16) ^ swz]) = v1;
    float pS = 0.f, pO = 0.f;
    {
      const _Float16* f0 = (const _Float16*)&v0;
      const _Float16* f1 = (const _Float16*)&v1;
      #pragma unroll
      for (int j = 0; j < 8; ++j) {
        const float a = (float)f0[j];
        const float bb = (float)f1[j];
        pS += a * wesb[skc * 8 + j] + bb * wesb[128 + skc * 8 + j];
        pO += a * weob[skc * 8 + j] + bb * weob[128 + skc * 8 + j];
      }
    }
    #pragma unroll
    for (int mm = 1; mm < 16; mm <<= 1) {
      pS += __shfl_xor(pS, mm, 16);
      pO += __shfl_xor(pO, mm, 16);
    }
    const float gs = sigf(dotS[b * NNODE + si] + pS);
    const float go = sigf(dotO[b * NNODE + ob] + pO);
    const _Float16 gsh = (_Float16)gs, goh = (_Float16)go;
    const _Float16* ns = nw + (b * NNODE + si) * 768;
    const _Float16* no_ = nw + (b * NNODE + ob) * 768;
    _Float16* giw = (_Float16*)(lds + GI_OFF) + srow * GI_STR;
    #pragma unroll
    for (int j = 0; j < 6; ++j) {
      const int c0 = skc * 8 + j * 128;
      const half8 a = *(const half8*)(ns + c0);
      const half8 bb = *(const half8*)(no_ + c0);
      half8 g;
      #pragma unroll
      for (int k = 0; k < 8; ++k) g[k] = gsh * a[k] + goh * bb[k];
      *(half8*)(giw + c0) = g;
    }
    __syncthreads();

    #pragma unroll
    for (int ksg = 0; ksg < 8; ++ksg) {
      half8 ah[4];
      #pragma unroll
      for (int rf = 0; rf < 4; ++rf)
        ah[rf] = *(const half8*)(&lds[((rf * 16 + lr) * 512 + ksg * 64 + lq * 16) ^ swm]);
      const int kk = 8 + ksg;
      const half8 br_ = *(const half8*)(wpe + (((0 * 16 + w) * 16 + kk) * 64 + l) * 8);
      const half8 bz_ = *(const half8*)(wpe + (((1 * 16 + w) * 16 + kk) * 64 + l) * 8);
      const half8 bn_ = *(const half8*)(wpe + (((2 * 16 + w) * 16 + kk) * 64 + l) * 8);
      #pragma unroll
      for (int rf = 0; rf < 4; ++rf)
        acc_r[rf] = __builtin_amdgcn_mfma_f32_16x16x32_f16(ah[rf], br_, acc_r[rf], 0, 0, 0);
      #pragma unroll
      for (int rf = 0; rf < 4; ++rf)
        acc_z[rf] = __builtin_amdgcn_mfma_f32_16x16x32_f16(ah[rf], bz_, acc_z[rf], 0, 0, 0);
      #pragma unroll
      for (int rf = 0; rf < 4; ++rf)
        acc_nh[rf] = __builtin_amdgcn_mfma_f32_16x16x32_f16(ah[rf], bn_, acc_nh[rf], 0, 0, 0);
    }

    const int col = w * 16 + lr;
    const float br = ebih[col] + ebhh[col];
    const float bz = ebih[256 + col] + ebhh[256 + col];
    const float bnx = ebih[512 + col];
    const float bnh = ebhh[512 + col];
    const _Float16* gir = (const _Float16*)(lds + GI_OFF);
    _Float16 sv[16];
    #pragma unroll
    for (int rf = 0; rf < 4; ++rf) {
      #pragma unroll
      for (int q = 0; q < 4; ++q) {
        const int rowl = rf * 16 + lq * 4 + q;
        const _Float16* gp = gir + rowl * GI_STR + col;
        const float r = sigf(acc_r[rf][q] + (float)gp[0] + br);
        const float z = sigf(acc_z[rf][q] + (float)gp[256] + bz);
        const float n = tanh_fast((float)gp[512] + bnx + r * (acc_nh[rf][q] + bnh));
        const float hv =
            (float)*(const _Float16*)(&lds[(rowl * 512 + col * 2) ^ ((rowl & 7) << 4)]);
        const float out = (1.0f - z) * n + z * hv;
        if constexpr (LAST) {
          ehf[(rb + rowl) * D_DIM + col] = out;
        } else {
          sv[rf * 4 + q] = (_Float16)out;
        }
      }
    }
    if constexpr (!LAST) {
      __syncthreads();
      #pragma unroll
      for (int rf = 0; rf < 4; ++rf) {
        #pragma unroll
        for (int q = 0; q < 4; ++q) {
          const int rowl = rf * 16 + lq * 4 + q;
          *(_Float16*)(&lds[(rowl * 512 + col * 2) ^ ((rowl & 7) << 4)]) = sv[rf * 4 + q];
        }
      }
      __syncthreads();
      #pragma unroll
      for (int p = 0; p < 2; ++p) {
        const int c = t + p * 1024;
        const int row = c >> 5;
        const int kc = c & 31;
        *(uint4*)(eh16 + (rb + row) * 256 + kc * 8) =
            *(const uint4*)(&lds[(row * 512 + kc * 16) ^ ((row & 7) << 4)]);
      }
    }
  } else {
    // ================= node GRU (f32 state, K-split h-first) =================
    const int rb = blockIdx.x * BM;
    const int rowg = rb + srow;

    {
      float4 pre[4];
      #pragma unroll
      for (int i = 0; i < 4; ++i)
        pre[i] = *(const float4*)(nh + rowg * D_DIM + (i >> 1) * 128 + skc * 8 + (i & 1) * 4);
      #pragma unroll
      for (int c = 0; c < 2; ++c) {
        half8 hh8;
        const float* f1 = (const float*)&pre[c * 2];
        #pragma unroll
        for (int j = 0; j < 8; ++j) hh8[j] = (_Float16)f1[j];
        *(half8*)(&lds[(srow * 1024 + 512 + c * 256 + skc * 16) ^ swz]) = hh8;
      }
    }
    __syncthreads();

    #pragma unroll
    for (int ksg = 0; ksg < 8; ++ksg) {
      half8 ah[4];
      #pragma unroll
      for (int rf = 0; rf < 4; ++rf)
        ah[rf] = *(const half8*)(&lds[((rf * 16 + lr) * 1024 + 512 + ksg * 64 + lq * 16) ^ swm]);
      const int kk = 8 + ksg;
      const half8 br_ = *(const half8*)(wpn + (((0 * 16 + w) * 16 + kk) * 64 + l) * 8);
      const half8 bz_ = *(const half8*)(wpn + (((1 * 16 + w) * 16 + kk) * 64 + l) * 8);
      const half8 bn_ = *(const half8*)(wpn + (((2 * 16 + w) * 16 + kk) * 64 + l) * 8);
      #pragma unroll
      for (int rf = 0; rf < 4; ++rf)
        acc_r[rf] = __builtin_amdgcn_mfma_f32_16x16x32_f16(ah[rf], br_, acc_r[rf], 0, 0, 0);
      #pragma unroll
      for (int rf = 0; rf < 4; ++rf)
        acc_z[rf] = __builtin_amdgcn_mfma_f32_16x16x32_f16(ah[rf], bz_, acc_z[rf], 0, 0, 0);
      #pragma unroll
      for (int rf = 0; rf < 4; ++rf)
        acc_nh[rf] = __builtin_amdgcn_mfma_f32_16x16x32_f16(ah[rf], bn_, acc_nh[rf], 0, 0, 0);
    }

    #pragma unroll
    for (int c = 0; c < 2; ++c) {
      half8 hx;
      #pragma unroll
      for (int pq = 0; pq < 2; ++pq) {
        const float4 a = *(const float4*)(nmsg + rowg * D_DIM + c * 128 + skc * 8 + pq * 4);
        hx[pq * 4 + 0] = (_Float16)a.x; hx[pq * 4 + 1] = (_Float16)a.y;
        hx[pq * 4 + 2] = (_Float16)a.z; hx[pq * 4 + 3] = (_Float16)a.w;
      }
      *(half8*)(&lds[(srow * 1024 + 0 + c * 256 + skc * 16) ^ swz]) = hx;
    }
    __syncthreads();
    #pragma unroll
    for (int ksg = 0; ksg < 8; ++ksg) {
      half8 ah[4];
      #pragma unroll
      for (int rf = 0; rf < 4; ++rf)
        ah[rf] = *(const half8*)(&lds[((rf * 16 + lr) * 1024 + 0 + ksg * 64 + lq * 16) ^ swm]);
      const half8 br_ = *(const half8*)(wpn + (((0 * 16 + w) * 16 + ksg) * 64 + l) * 8);
      const half8 bz_ = *(const half8*)(wpn + (((1 * 16 + w) * 16 + ksg) * 64 + l) * 8);
      const half8 bn_ = *(const half8*)(wpn + (((2 * 16 + w) * 16 + ksg) * 64 + l) * 8);
      #pragma unroll
      for (int rf = 0; rf < 4; ++rf)
        acc_r[rf] = __builtin_amdgcn_mfma_f32_16x16x32_f16(ah[rf], br_, acc_r[rf], 0, 0, 0);
      #pragma unroll
      for (int rf = 0; rf < 4; ++rf)
        acc_z[rf] = __builtin_amdgcn_mfma_f32_16x16x32_f16(ah[rf], bz_, acc_z[rf], 0, 0, 0);
      #pragma unroll
      for (int rf = 0; rf < 4; ++rf)
        acc_nx[rf] = __builtin_amdgcn_mfma_f32_16x16x32_f16(ah[rf], bn_, acc_nx[rf], 0, 0, 0);
    }

    const int col = w * 16 + lr;
    const float br = nbih[col] + nbhh[col];
    const float bz = nbih[256 + col] + nbhh[256 + col];
    const float bnx = nbih[512 + col];
    const float bnh = nbhh[512 + col];
    unsigned char* reg = lds + NT_OFF;
    #pragma unroll
    for (int rf = 0; rf < 4; ++rf) {
      #pragma unroll
      for (int q = 0; q < 4; ++q) {
        const int rowl = rf * 16 + lq * 4 + q;
        const float r = sigf(acc_r[rf][q] + br);
        const float z = sigf(acc_z[rf][q] + bz);
        const float n = tanh_fast(acc_nx[rf][q] + bnx + r * (acc_nh[rf][q] + bnh));
        const float hv = nh[(rb + rowl) * D_DIM + col];
        const float out = (1.0f - z) * n + z * hv;
        nh[(rb + rowl) * D_DIM + col] = out;
        if constexpr (!LAST)
          *(_Float16*)(&reg[(rowl * 512 + col * 2) ^ ((rowl & 7) << 4)]) = (_Float16)out;
      }
    }
    if constexpr (!LAST) {
      __syncthreads();
      nw_tail(reg, rb, t, wpe, wnp, wes, weo, dAo, dSo, dOo, nwo);
    }
  }
}

// node_msg from eh16: gN inline.
__global__ __launch_bounds__(256) void node_msg_kernel(
    const _Float16* __restrict__ eh16, const float* __restrict__ wnp,
    const float* __restrict__ dotA, float* __restrict__ nmsg) {
  __shared__ float sh[3][256];
  const int nr = blockIdx.x;
  const int b = nr >> 5;
  const int n = nr & 31;
  const int wv = threadIdx.x >> 6;
  const int l = threadIdx.x & 63;
  const int base = b * NEDGE;
  const float4 w1b = ((const float4*)(wnp + 256))[l];

  float4 acc = {0.f, 0.f, 0.f, 0.f};
  for (int k = wv; k < 62; k += 4) {
    int e, sub;
    if (k < 31) {
      e = base + n * 31 + k;
      sub = n;
    } else {
      int i = k - 31;
      const int ip = (i < n) ? i : (i + 1);
      e = base + ip * 31 + ((n < ip) ? n : (n - 1));
      sub = ip;
    }
    const half4v hv4 = ((const half4v*)(eh16 + e * 256))[l];
    float4 ev;
    ev.x = (float)hv4[0]; ev.y = (float)hv4[1];
    ev.z = (float)hv4[2]; ev.w = (float)hv4[3];
    float p = dot4(ev, w1b);
    #pragma unroll
    for (int mm = 32; mm > 0; mm >>= 1) p += __shfl_xor(p, mm, 64);
    const float gN = sigf(dotA[b * NNODE + sub] + p);
    acc.x += gN * ev.x; acc.y += gN * ev.y; acc.z += gN * ev.z; acc.w += gN * ev.w;
  }
  if (wv > 0) *(float4*)(&sh[wv - 1][l * 4]) = acc;
  __syncthreads();
  if (wv == 0) {
    #pragma unroll
    for (int v = 0; v < 3; ++v) {
      const float4 o = *(const float4*)(&sh[v][l * 4]);
      acc.x += o.x; acc.y += o.y; acc.z += o.z; acc.w += o.w;
    }
    *(float4*)(nmsg + nr * D_DIM + l * 4) = acc;
  }
}

extern "C" void kernel_launch(void* const* d_in, const int* in_sizes, int n_in,
                              void* d_out, int out_size, void* d_ws, size_t ws_size,
                              hipStream_t stream) {
  const float* node_latents = (const float*)d_in[0];
  const float* edge_latents = (const float*)d_in[1];
  const float* node_Wih = (const float*)d_in[2];
  const float* node_Whh = (const float*)d_in[3];
  const float* node_bih = (const float*)d_in[4];
  const float* node_bhh = (const float*)d_in[5];
  const float* edge_Wih = (const float*)d_in[6];
  const float* edge_Whh = (const float*)d_in[7];
  const float* edge_bih = (const float*)d_in[8];
  const float* edge_bhh = (const float*)d_in[9];
  const float* w_node_pool = (const float*)d_in[10];
  const float* w_edge_sub = (const float*)d_in[11];
  const float* w_edge_obj = (const float*)d_in[12];

  float* nh = (float*)d_out;
  float* eh = (float*)d_out + NODE_ROWS * D_DIM;

  const int WPLANE = 48 * 16 * 64 * 8;  // 768KB
  _Float16* ph_n = (_Float16*)d_ws;
  _Float16* ph_e = ph_n + WPLANE;
  _Float16* NW0 = ph_e + WPLANE;                   // 6 MB
  _Float16* NW1 = NW0 + NODE_ROWS * 768;           // 6 MB
  _Float16* eh16 = NW1 + NODE_ROWS * 768;          // 65 MB
  float* fw = (float*)(eh16 + (size_t)EDGE_ROWS * D_DIM);
  float* dotA0 = fw; fw += NODE_ROWS;
  float* dotS0 = fw; fw += NODE_ROWS;
  float* dotO0 = fw; fw += NODE_ROWS;
  float* dotA1 = fw; fw += NODE_ROWS;
  float* dotS1 = fw; fw += NODE_ROWS;
  float* dotO1 = fw; fw += NODE_ROWS;
  float* node_msg = fw; fw += NODE_ROWS * D_DIM;   // total ~83 MB

  dim3 pg(48, 16);
  pack_w<<<pg, 64, 0, stream>>>(node_Wih, node_Whh, ph_n);
  pack_w<<<pg, 64, 0, stream>>>(edge_Wih, edge_Whh, ph_e);

  // init: tail writes gen0
  gru_init<<<NGRID + EGRID, 1024, 0, stream>>>(
      edge_latents, node_latents, eh16, nh, ph_e, ph_n,
      edge_bih, edge_bhh, node_bih, node_bhh,
      w_node_pool, w_edge_sub, w_edge_obj, dotA0, dotS0, dotO0, NW0);

  _Float16* NWg[2] = {NW0, NW1};
  float* dAg[2] = {dotA0, dotA1};
  float* dSg[2] = {dotS0, dotS1};
  float* dOg[2] = {dotO0, dotO1};

  for (int it = 0; it < 3; ++it) {
    const int gi = it & 1;        // generation read this iteration
    const int go = gi ^ 1;        // generation written by the tail
    node_msg_kernel<<<NODE_ROWS, 256, 0, stream>>>(eh16, w_node_pool, dAg[gi], node_msg);
    if (it < 2)
      gru_iter<false><<<NGRID + EGRID, 1024, 0, stream>>>(
          eh16, eh, nh, node_msg, ph_e, ph_n,
          edge_bih, edge_bhh, node_bih, node_bhh,
          w_edge_sub + 256, w_edge_obj + 256, dSg[gi], dOg[gi], NWg[gi],
          w_node_pool, w_edge_sub, w_edge_obj, dAg[go], dSg[go], dOg[go], NWg[go]);
    else
      gru_iter<true><<<NGRID + EGRID, 1024, 0, stream>>>(
          eh16, eh, nh, node_msg, ph_e, ph_n,
          edge_bih, edge_bhh, node_bih, node_bhh,
          w_edge_sub + 256, w_edge_obj + 256, dSg[gi], dOg[gi], NWg[gi],
          w_node_pool, w_edge_sub, w_edge_obj, dAg[go], dSg[go], dOg[go], NWg[go]);
  }
}